// Round 9
// baseline (605.146 us; speedup 1.0000x reference)
//
#include <hip/hip_runtime.h>
#include <math.h>

#define N_NODES 50000
#define N_EDGES 1600000
#define ETOT (N_EDGES + N_NODES)
#define HC 128
#define HEADS 4
#define HID 32
#define NEG_SLOPE 0.2f
#define NPB 32                               // nodes per bucket (aligned)
#define NBUCKETS ((N_NODES + NPB - 1) / NPB) // 1563
#define CHUNK 8192
#define NCHUNK ((ETOT + CHUNK - 1) / CHUNK)  // 202
#define LOG2E 1.4426950408889634f
#define NEGBIG (-1e30f)

// ---------------- CSR build ----------------

__global__ __launch_bounds__(256) void hist_kernel(const int* __restrict__ dstArr, int* __restrict__ deg) {
    int i = blockIdx.x * 256 + threadIdx.x;
    if (i >= ETOT) return;
    int d = (i < N_EDGES) ? dstArr[i] : (i - N_EDGES);
    atomicAdd(&deg[d], 1);
}

__global__ __launch_bounds__(1024) void scanA_kernel(const int* __restrict__ deg,
                                                     int* __restrict__ rowStart, int* __restrict__ blockSum) {
    __shared__ int buf[1024];
    int i = blockIdx.x * 1024 + threadIdx.x;
    int v = (i < N_NODES) ? deg[i] : 0;
    buf[threadIdx.x] = v;
    __syncthreads();
    for (int off = 1; off < 1024; off <<= 1) {
        int t = (threadIdx.x >= off) ? buf[threadIdx.x - off] : 0;
        __syncthreads();
        buf[threadIdx.x] += t;
        __syncthreads();
    }
    if (i < N_NODES) rowStart[i] = buf[threadIdx.x] - v;   // exclusive, pre-offset
    if (threadIdx.x == 1023) blockSum[blockIdx.x] = buf[1023];
}

__global__ void scanB_kernel(const int* __restrict__ blockSum, int* __restrict__ blockOff, int nb) {
    if (threadIdx.x == 0 && blockIdx.x == 0) {
        int acc = 0;
        for (int j = 0; j < nb; j++) { blockOff[j] = acc; acc += blockSum[j]; }
    }
}

// adds block offsets; also emits bucket cursors (rowStart[b*32]) and the sentinel
__global__ __launch_bounds__(1024) void scanC_kernel(int* __restrict__ rowStart, const int* __restrict__ blockOff,
                                                     int* __restrict__ bucketCursor) {
    int i = blockIdx.x * 1024 + threadIdx.x;
    if (i < N_NODES) {
        int v = rowStart[i] + blockOff[blockIdx.x];
        rowStart[i] = v;
        if ((i & (NPB - 1)) == 0) bucketCursor[i >> 5] = v;
    }
    if (i == 0) rowStart[N_NODES] = ETOT;   // sentinel
}

// Pass 1: chunked counting-sort scatter to bucket granularity.
__global__ __launch_bounds__(256) void chunk_scatter_kernel(const int* __restrict__ srcArr, const int* __restrict__ dstArr,
                                                            int* __restrict__ bucketCursor, int* __restrict__ E) {
    __shared__ int hist[NBUCKETS];   // then reused as running cursor
    int c0 = blockIdx.x * CHUNK;
    int c1 = min(c0 + CHUNK, ETOT);
    for (int b = threadIdx.x; b < NBUCKETS; b += 256) hist[b] = 0;
    __syncthreads();

    int myP[CHUNK / 256];   // packed src | (d<<16)
    int cnt = 0;
    for (int i = c0 + threadIdx.x; i < c1; i += 256) {
        int s, d;
        if (i < N_EDGES) { s = srcArr[i]; d = dstArr[i]; }
        else             { s = i - N_EDGES; d = s; }
        myP[cnt] = s | (d << 16);
        cnt++;
        atomicAdd(&hist[d >> 5], 1);
    }
    __syncthreads();
    for (int b = threadIdx.x; b < NBUCKETS; b += 256) {
        int h = hist[b];
        hist[b] = (h > 0) ? atomicAdd(&bucketCursor[b], h) : 0;
    }
    __syncthreads();
    for (int k = 0; k < cnt; k++) {
        int pe = myP[k];
        int pos = atomicAdd(&hist[((unsigned)pe) >> 21], 1);   // bucket = d>>5
        E[pos] = pe;
    }
}

// Pass 2: one block per bucket; emits BYTE offsets src*512 into srcOff
__global__ __launch_bounds__(256) void csr_scatter_kernel(const int* __restrict__ E, const int* __restrict__ rowStart,
                                                          int* __restrict__ srcOff) {
    __shared__ int lcur[NPB];
    int b = blockIdx.x;
    int n0 = b * NPB;
    int nend = min(n0 + NPB, N_NODES);
    if (threadIdx.x < nend - n0) lcur[threadIdx.x] = rowStart[n0 + threadIdx.x];
    __syncthreads();
    int e0 = rowStart[n0];
    int e1 = rowStart[nend];
    for (int i = e0 + threadIdx.x; i < e1; i += 256) {
        int pe = E[i];
        int pos = atomicAdd(&lcur[(pe >> 16) & (NPB - 1)], 1);
        srcOff[pos] = (pe & 0xFFFF) << 9;     // byte offset into XL (row = 512 B)
    }
}

// ---------------- GEMM: XL = x@Wl + bl, XR = x@Wr + br ----------------
// grid = (ceil(N/64), 4). blockIdx.y selects 64-col tile of [Wl | Wr] (256 cols).
// k-step of 4 with float4 LDS reads on both A and B: 8 ds_read_b128 per 64 FMA.

__global__ __launch_bounds__(256) void gemm_kernel(const float* __restrict__ x,
    const float* __restrict__ Wl, const float* __restrict__ bl,
    const float* __restrict__ Wr, const float* __restrict__ br,
    float* __restrict__ XL, float* __restrict__ XR) {
    __shared__ float As[64][76];   // 76 words: 16B-aligned rows, 2-way bank alias on 4-row reads (free)
    __shared__ float Bs[64][64];
    int t = threadIdx.x;
    int rb = blockIdx.x * 64;
    int cb = blockIdx.y * 64;
    const float* W; const float* bias; float* out; int c0;
    if (cb < HC) { W = Wl; bias = bl; out = XL; c0 = cb; }
    else         { W = Wr; bias = br; out = XR; c0 = cb - HC; }
    int tx = t & 15, ty = t >> 4;
    float acc[4][4];
#pragma unroll
    for (int i = 0; i < 4; i++)
#pragma unroll
        for (int j = 0; j < 4; j++) acc[i][j] = 0.f;

    for (int kt = 0; kt < 2; kt++) {
#pragma unroll
        for (int it = 0; it < 4; it++) {
            int idx = it * 256 + t;
            int r = idx >> 4, f = idx & 15;
            int gr = rb + r;
            float4 v = make_float4(0.f, 0.f, 0.f, 0.f);
            if (gr < N_NODES) v = *reinterpret_cast<const float4*>(&x[gr * HC + kt * 64 + f * 4]);
            *reinterpret_cast<float4*>(&As[r][f * 4]) = v;
        }
#pragma unroll
        for (int it = 0; it < 4; it++) {
            int idx = it * 256 + t;
            int k = idx >> 4, f = idx & 15;
            float4 v = *reinterpret_cast<const float4*>(&W[(kt * 64 + k) * HC + c0 + f * 4]);
            *reinterpret_cast<float4*>(&Bs[k][f * 4]) = v;
        }
        __syncthreads();
#pragma unroll 4
        for (int k4 = 0; k4 < 16; k4++) {
            float4 b0 = *reinterpret_cast<const float4*>(&Bs[k4 * 4 + 0][tx * 4]);
            float4 b1 = *reinterpret_cast<const float4*>(&Bs[k4 * 4 + 1][tx * 4]);
            float4 b2 = *reinterpret_cast<const float4*>(&Bs[k4 * 4 + 2][tx * 4]);
            float4 b3 = *reinterpret_cast<const float4*>(&Bs[k4 * 4 + 3][tx * 4]);
#pragma unroll
            for (int i = 0; i < 4; i++) {
                float4 av = *reinterpret_cast<const float4*>(&As[ty * 4 + i][k4 * 4]);
                acc[i][0] += av.x * b0.x + av.y * b1.x + av.z * b2.x + av.w * b3.x;
                acc[i][1] += av.x * b0.y + av.y * b1.y + av.z * b2.y + av.w * b3.y;
                acc[i][2] += av.x * b0.z + av.y * b1.z + av.z * b2.z + av.w * b3.z;
                acc[i][3] += av.x * b0.w + av.y * b1.w + av.z * b2.w + av.w * b3.w;
            }
        }
        __syncthreads();
    }
    float4 bb = *reinterpret_cast<const float4*>(&bias[c0 + tx * 4]);
#pragma unroll
    for (int i = 0; i < 4; i++) {
        int gr = rb + ty * 4 + i;
        if (gr < N_NODES) {
            float4 o;
            o.x = acc[i][0] + bb.x; o.y = acc[i][1] + bb.y;
            o.z = acc[i][2] + bb.z; o.w = acc[i][3] + bb.w;
            *reinterpret_cast<float4*>(&out[gr * HC + c0 + tx * 4]) = o;
        }
    }
}

// ---------------- Fused GAT: 2 edges/wave, float4 lanes, direct-exp, 8 chains ----------------
// (r8 kernel, unchanged — at the gather roofline for this layout)

__device__ __forceinline__ float score4(float4 xl, float4 xr, float4 a) {
    float hx = xl.x + xr.x, hy = xl.y + xr.y, hz = xl.z + xr.z, hw = xl.w + xr.w;
    hx = fmaxf(hx, NEG_SLOPE * hx);
    hy = fmaxf(hy, NEG_SLOPE * hy);
    hz = fmaxf(hz, NEG_SLOPE * hz);
    hw = fmaxf(hw, NEG_SLOPE * hw);
    float c = ((a.x * hx + a.y * hy) + (a.z * hz + a.w * hw));
    c += __shfl_xor(c, 1);
    c += __shfl_xor(c, 2);
    c += __shfl_xor(c, 4);     // 8-lane head group holds e_h * log2e
    return fminf(c, 120.f);    // overflow insurance
}

__device__ __forceinline__ void upd4(float c, float4 xl, float& z, float4& acc) {
    float w = exp2f(c);
    z += w;
    acc.x += w * xl.x;
    acc.y += w * xl.y;
    acc.z += w * xl.z;
    acc.w += w * xl.w;
}

__global__ __launch_bounds__(256) void gat_fused_kernel(const float* __restrict__ XL,
    const float* __restrict__ XR, const float* __restrict__ att,
    const int* __restrict__ rowStart, const int* __restrict__ srcOff,
    const float* __restrict__ bvec, float* __restrict__ out, int applyElu) {
    int wv = threadIdx.x >> 6;
    int l = threadIdx.x & 63;
    int half = l >> 5;
    int cb = l & 31;
    int n = blockIdx.x * 4 + wv;
    if (n >= N_NODES) return;
    int s0 = rowStart[n], s1 = rowStart[n + 1];

    float4 xr4 = *reinterpret_cast<const float4*>(&XR[n * HC + 4 * cb]);
    float4 a4  = *reinterpret_cast<const float4*>(&att[4 * cb]);
    a4.x *= LOG2E; a4.y *= LOG2E; a4.z *= LOG2E; a4.w *= LOG2E;
    const char* XLb = reinterpret_cast<const char*>(XL) + 16 * cb;

    float z = 0.f;
    float4 acc = make_float4(0.f, 0.f, 0.f, 0.f);

    int p = s0;
    for (; p + 16 <= s1; p += 16) {
        int oA = srcOff[p      + half];
        int oB = srcOff[p + 2  + half];
        int oC = srcOff[p + 4  + half];
        int oD = srcOff[p + 6  + half];
        int oE = srcOff[p + 8  + half];
        int oF = srcOff[p + 10 + half];
        int oG = srcOff[p + 12 + half];
        int oH = srcOff[p + 14 + half];
        float4 xlA = *reinterpret_cast<const float4*>(XLb + (size_t)oA);
        float4 xlB = *reinterpret_cast<const float4*>(XLb + (size_t)oB);
        float4 xlC = *reinterpret_cast<const float4*>(XLb + (size_t)oC);
        float4 xlD = *reinterpret_cast<const float4*>(XLb + (size_t)oD);
        float4 xlE = *reinterpret_cast<const float4*>(XLb + (size_t)oE);
        float4 xlF = *reinterpret_cast<const float4*>(XLb + (size_t)oF);
        float4 xlG = *reinterpret_cast<const float4*>(XLb + (size_t)oG);
        float4 xlH = *reinterpret_cast<const float4*>(XLb + (size_t)oH);
        float cA = score4(xlA, xr4, a4);
        float cB = score4(xlB, xr4, a4);
        float cC = score4(xlC, xr4, a4);
        float cD = score4(xlD, xr4, a4);
        upd4(cA, xlA, z, acc);
        upd4(cB, xlB, z, acc);
        upd4(cC, xlC, z, acc);
        upd4(cD, xlD, z, acc);
        float cE = score4(xlE, xr4, a4);
        float cF = score4(xlF, xr4, a4);
        float cG = score4(xlG, xr4, a4);
        float cH = score4(xlH, xr4, a4);
        upd4(cE, xlE, z, acc);
        upd4(cF, xlF, z, acc);
        upd4(cG, xlG, z, acc);
        upd4(cH, xlH, z, acc);
    }
    for (; p + 8 <= s1; p += 8) {
        int oA = srcOff[p     + half];
        int oB = srcOff[p + 2 + half];
        int oC = srcOff[p + 4 + half];
        int oD = srcOff[p + 6 + half];
        float4 xlA = *reinterpret_cast<const float4*>(XLb + (size_t)oA);
        float4 xlB = *reinterpret_cast<const float4*>(XLb + (size_t)oB);
        float4 xlC = *reinterpret_cast<const float4*>(XLb + (size_t)oC);
        float4 xlD = *reinterpret_cast<const float4*>(XLb + (size_t)oD);
        float cA = score4(xlA, xr4, a4);
        float cB = score4(xlB, xr4, a4);
        float cC = score4(xlC, xr4, a4);
        float cD = score4(xlD, xr4, a4);
        upd4(cA, xlA, z, acc);
        upd4(cB, xlB, z, acc);
        upd4(cC, xlC, z, acc);
        upd4(cD, xlD, z, acc);
    }
    for (; p + 2 <= s1; p += 2) {
        int o = srcOff[p + half];
        float4 xl4 = *reinterpret_cast<const float4*>(XLb + (size_t)o);
        float c = score4(xl4, xr4, a4);
        upd4(c, xl4, z, acc);
    }
    if (p < s1) {
        int o = srcOff[p];
        float4 xl4 = *reinterpret_cast<const float4*>(XLb + (size_t)o);
        float c = score4(xl4, xr4, a4);
        if (half) c = NEGBIG;
        upd4(c, xl4, z, acc);
    }

    z     += __shfl_xor(z, 32);
    acc.x += __shfl_xor(acc.x, 32);
    acc.y += __shfl_xor(acc.y, 32);
    acc.z += __shfl_xor(acc.z, 32);
    acc.w += __shfl_xor(acc.w, 32);

    if (half == 0) {
        float zinv = 1.f / z;
        float4 b4 = *reinterpret_cast<const float4*>(&bvec[4 * cb]);
        float4 o4;
        o4.x = acc.x * zinv + b4.x;
        o4.y = acc.y * zinv + b4.y;
        o4.z = acc.z * zinv + b4.z;
        o4.w = acc.w * zinv + b4.w;
        if (applyElu) {
            o4.x = o4.x > 0.f ? o4.x : (__expf(o4.x) - 1.f);
            o4.y = o4.y > 0.f ? o4.y : (__expf(o4.y) - 1.f);
            o4.z = o4.z > 0.f ? o4.z : (__expf(o4.z) - 1.f);
            o4.w = o4.w > 0.f ? o4.w : (__expf(o4.w) - 1.f);
        }
        *reinterpret_cast<float4*>(&out[n * HC + 4 * cb]) = o4;
    }
}

// ---------------- launch ----------------

extern "C" void kernel_launch(void* const* d_in, const int* in_sizes, int n_in,
                              void* d_out, int out_size, void* d_ws, size_t ws_size,
                              hipStream_t stream) {
    const float* x = (const float*)d_in[0];
    const int* ei = (const int*)d_in[1];
    const int* srcArr = ei;
    const int* dstArr = ei + N_EDGES;

    char* ws = (char*)d_ws;
    size_t off = 0;
    auto alloc = [&](size_t bytes) -> void* {
        void* p = ws + off;
        off = (off + bytes + 511) & ~(size_t)511;
        return p;
    };
    float* P       = (float*)alloc((size_t)N_NODES * HC * 4);
    float* XL      = (float*)alloc((size_t)N_NODES * HC * 4);
    float* XR      = (float*)alloc((size_t)N_NODES * HC * 4);
    int* deg       = (int*)alloc((size_t)N_NODES * 4);
    int* rowStart  = (int*)alloc((size_t)(N_NODES + 1) * 4);
    int* blockSum  = (int*)alloc(64 * 4);
    int* blockOff  = (int*)alloc(64 * 4);
    int* bucketCur = (int*)alloc((size_t)NBUCKETS * 4);
    int* E         = (int*)alloc((size_t)ETOT * 4);
    int* srcOff    = (int*)alloc((size_t)ETOT * 4);

    const int NSCAN = (N_NODES + 1023) / 1024;   // 49

    hipMemsetAsync(deg, 0, (size_t)N_NODES * 4, stream);
    hist_kernel<<<(ETOT + 255) / 256, 256, 0, stream>>>(dstArr, deg);
    scanA_kernel<<<NSCAN, 1024, 0, stream>>>(deg, rowStart, blockSum);
    scanB_kernel<<<1, 64, 0, stream>>>(blockSum, blockOff, NSCAN);
    scanC_kernel<<<NSCAN, 1024, 0, stream>>>(rowStart, blockOff, bucketCur);
    chunk_scatter_kernel<<<NCHUNK, 256, 0, stream>>>(srcArr, dstArr, bucketCur, E);
    csr_scatter_kernel<<<NBUCKETS, 256, 0, stream>>>(E, rowStart, srcOff);

    for (int lyr = 0; lyr < 3; lyr++) {
        const float* xin = (lyr == 0) ? x : P;
        float* xout = (lyr == 2) ? (float*)d_out : P;
        const float* Wl  = (const float*)d_in[2 + 6 * lyr + 0];
        const float* bl  = (const float*)d_in[2 + 6 * lyr + 1];
        const float* Wr  = (const float*)d_in[2 + 6 * lyr + 2];
        const float* br  = (const float*)d_in[2 + 6 * lyr + 3];
        const float* att = (const float*)d_in[2 + 6 * lyr + 4];
        const float* bb  = (const float*)d_in[2 + 6 * lyr + 5];

        dim3 ggrid((N_NODES + 63) / 64, 4);
        gemm_kernel<<<ggrid, 256, 0, stream>>>(xin, Wl, bl, Wr, br, XL, XR);

        int nb = (N_NODES + 3) / 4;
        gat_fused_kernel<<<nb, 256, 0, stream>>>(XL, XR, att, rowStart, srcOff, bb, xout, lyr < 2 ? 1 : 0);
    }
}

// Round 10
// 597.293 us; speedup vs baseline: 1.0131x; 1.0131x over previous
//
#include <hip/hip_runtime.h>
#include <math.h>

#define N_NODES 50000
#define N_EDGES 1600000
#define ETOT (N_EDGES + N_NODES)
#define HC 128
#define HEADS 4
#define HID 32
#define NEG_SLOPE 0.2f
#define NPB 32                               // nodes per bucket (aligned)
#define NBUCKETS ((N_NODES + NPB - 1) / NPB) // 1563
#define CHUNK 8192
#define NCHUNK ((ETOT + CHUNK - 1) / CHUNK)  // 202
#define LOG2E 1.4426950408889634f
#define NEGBIG (-1e30f)

// ---------------- CSR build ----------------

__global__ __launch_bounds__(256) void hist_kernel(const int* __restrict__ dstArr, int* __restrict__ deg) {
    int i = blockIdx.x * 256 + threadIdx.x;
    if (i >= ETOT) return;
    int d = (i < N_EDGES) ? dstArr[i] : (i - N_EDGES);
    atomicAdd(&deg[d], 1);
}

__global__ __launch_bounds__(1024) void scanA_kernel(const int* __restrict__ deg,
                                                     int* __restrict__ rowStart, int* __restrict__ blockSum) {
    __shared__ int buf[1024];
    int i = blockIdx.x * 1024 + threadIdx.x;
    int v = (i < N_NODES) ? deg[i] : 0;
    buf[threadIdx.x] = v;
    __syncthreads();
    for (int off = 1; off < 1024; off <<= 1) {
        int t = (threadIdx.x >= off) ? buf[threadIdx.x - off] : 0;
        __syncthreads();
        buf[threadIdx.x] += t;
        __syncthreads();
    }
    if (i < N_NODES) rowStart[i] = buf[threadIdx.x] - v;   // exclusive, pre-offset
    if (threadIdx.x == 1023) blockSum[blockIdx.x] = buf[1023];
}

__global__ void scanB_kernel(const int* __restrict__ blockSum, int* __restrict__ blockOff, int nb) {
    if (threadIdx.x == 0 && blockIdx.x == 0) {
        int acc = 0;
        for (int j = 0; j < nb; j++) { blockOff[j] = acc; acc += blockSum[j]; }
    }
}

// adds block offsets; also emits bucket cursors (rowStart[b*32]) and the sentinel
__global__ __launch_bounds__(1024) void scanC_kernel(int* __restrict__ rowStart, const int* __restrict__ blockOff,
                                                     int* __restrict__ bucketCursor) {
    int i = blockIdx.x * 1024 + threadIdx.x;
    if (i < N_NODES) {
        int v = rowStart[i] + blockOff[blockIdx.x];
        rowStart[i] = v;
        if ((i & (NPB - 1)) == 0) bucketCursor[i >> 5] = v;
    }
    if (i == 0) rowStart[N_NODES] = ETOT;   // sentinel
}

// Pass 1: chunked counting-sort scatter to bucket granularity.
__global__ __launch_bounds__(256) void chunk_scatter_kernel(const int* __restrict__ srcArr, const int* __restrict__ dstArr,
                                                            int* __restrict__ bucketCursor, int* __restrict__ E) {
    __shared__ int hist[NBUCKETS];   // then reused as running cursor
    int c0 = blockIdx.x * CHUNK;
    int c1 = min(c0 + CHUNK, ETOT);
    for (int b = threadIdx.x; b < NBUCKETS; b += 256) hist[b] = 0;
    __syncthreads();

    int myP[CHUNK / 256];   // packed src | (d<<16)
    int cnt = 0;
    for (int i = c0 + threadIdx.x; i < c1; i += 256) {
        int s, d;
        if (i < N_EDGES) { s = srcArr[i]; d = dstArr[i]; }
        else             { s = i - N_EDGES; d = s; }
        myP[cnt] = s | (d << 16);
        cnt++;
        atomicAdd(&hist[d >> 5], 1);
    }
    __syncthreads();
    for (int b = threadIdx.x; b < NBUCKETS; b += 256) {
        int h = hist[b];
        hist[b] = (h > 0) ? atomicAdd(&bucketCursor[b], h) : 0;
    }
    __syncthreads();
    for (int k = 0; k < cnt; k++) {
        int pe = myP[k];
        int pos = atomicAdd(&hist[((unsigned)pe) >> 21], 1);   // bucket = d>>5
        E[pos] = pe;
    }
}

// Pass 2: one block per bucket; emits BYTE offsets src*512 into srcOff
__global__ __launch_bounds__(256) void csr_scatter_kernel(const int* __restrict__ E, const int* __restrict__ rowStart,
                                                          int* __restrict__ srcOff) {
    __shared__ int lcur[NPB];
    int b = blockIdx.x;
    int n0 = b * NPB;
    int nend = min(n0 + NPB, N_NODES);
    if (threadIdx.x < nend - n0) lcur[threadIdx.x] = rowStart[n0 + threadIdx.x];
    __syncthreads();
    int e0 = rowStart[n0];
    int e1 = rowStart[nend];
    for (int i = e0 + threadIdx.x; i < e1; i += 256) {
        int pe = E[i];
        int pos = atomicAdd(&lcur[(pe >> 16) & (NPB - 1)], 1);
        srcOff[pos] = (pe & 0xFFFF) << 9;     // byte offset into XL (row = 512 B)
    }
}

// ---------------- GEMM: 128x128 tile, 8x8 per thread, K-step 32 ----------------
// grid = (ceil(N/128), 2); y=0: XL = x@Wl+bl, y=1: XR = x@Wr+br.
// Per thread per k: 8 broadcast A reads + 2 b128 B reads = 64 B for 64 FMA (1 B/FMA).

__global__ __launch_bounds__(256) void gemm_kernel(const float* __restrict__ x,
    const float* __restrict__ Wl, const float* __restrict__ bl,
    const float* __restrict__ Wr, const float* __restrict__ br,
    float* __restrict__ XL, float* __restrict__ XR) {
    __shared__ float As[128][36];   // 36-word rows: 16B-aligned, ty-groups 2-way bank alias (free)
    __shared__ float Bs[32][128];
    int t = threadIdx.x;
    int rb = blockIdx.x * 128;
    const float* W; const float* bias; float* out;
    if (blockIdx.y == 0) { W = Wl; bias = bl; out = XL; }
    else                 { W = Wr; bias = br; out = XR; }
    int tx = t & 15, ty = t >> 4;

    float acc00[4][4], acc01[4][4], acc10[4][4], acc11[4][4];
#pragma unroll
    for (int i = 0; i < 4; i++)
#pragma unroll
        for (int j = 0; j < 4; j++) { acc00[i][j] = 0.f; acc01[i][j] = 0.f; acc10[i][j] = 0.f; acc11[i][j] = 0.f; }

    for (int kt = 0; kt < 4; kt++) {
        // A tile: 128 rows x 32 k  (1024 float4, 4 per thread)
#pragma unroll
        for (int it = 0; it < 4; it++) {
            int idx = it * 256 + t;
            int r = idx >> 3, f = idx & 7;
            int gr = rb + r;
            float4 v = make_float4(0.f, 0.f, 0.f, 0.f);
            if (gr < N_NODES) v = *reinterpret_cast<const float4*>(&x[gr * HC + kt * 32 + f * 4]);
            *reinterpret_cast<float4*>(&As[r][f * 4]) = v;
        }
        // B tile: 32 k x 128 cols (1024 float4, 4 per thread)
#pragma unroll
        for (int it = 0; it < 4; it++) {
            int idx = it * 256 + t;
            int k = idx >> 5, f = idx & 31;
            *reinterpret_cast<float4*>(&Bs[k][f * 4]) =
                *reinterpret_cast<const float4*>(&W[(kt * 32 + k) * HC + f * 4]);
        }
        __syncthreads();
#pragma unroll 4
        for (int k = 0; k < 32; k++) {
            float4 b0 = *reinterpret_cast<const float4*>(&Bs[k][tx * 4]);
            float4 b1 = *reinterpret_cast<const float4*>(&Bs[k][64 + tx * 4]);
            float a0 = As[ty * 4 + 0][k];
            float a1 = As[ty * 4 + 1][k];
            float a2 = As[ty * 4 + 2][k];
            float a3 = As[ty * 4 + 3][k];
            float a4 = As[64 + ty * 4 + 0][k];
            float a5 = As[64 + ty * 4 + 1][k];
            float a6 = As[64 + ty * 4 + 2][k];
            float a7 = As[64 + ty * 4 + 3][k];
            acc00[0][0] += a0 * b0.x; acc00[0][1] += a0 * b0.y; acc00[0][2] += a0 * b0.z; acc00[0][3] += a0 * b0.w;
            acc00[1][0] += a1 * b0.x; acc00[1][1] += a1 * b0.y; acc00[1][2] += a1 * b0.z; acc00[1][3] += a1 * b0.w;
            acc00[2][0] += a2 * b0.x; acc00[2][1] += a2 * b0.y; acc00[2][2] += a2 * b0.z; acc00[2][3] += a2 * b0.w;
            acc00[3][0] += a3 * b0.x; acc00[3][1] += a3 * b0.y; acc00[3][2] += a3 * b0.z; acc00[3][3] += a3 * b0.w;
            acc01[0][0] += a0 * b1.x; acc01[0][1] += a0 * b1.y; acc01[0][2] += a0 * b1.z; acc01[0][3] += a0 * b1.w;
            acc01[1][0] += a1 * b1.x; acc01[1][1] += a1 * b1.y; acc01[1][2] += a1 * b1.z; acc01[1][3] += a1 * b1.w;
            acc01[2][0] += a2 * b1.x; acc01[2][1] += a2 * b1.y; acc01[2][2] += a2 * b1.z; acc01[2][3] += a2 * b1.w;
            acc01[3][0] += a3 * b1.x; acc01[3][1] += a3 * b1.y; acc01[3][2] += a3 * b1.z; acc01[3][3] += a3 * b1.w;
            acc10[0][0] += a4 * b0.x; acc10[0][1] += a4 * b0.y; acc10[0][2] += a4 * b0.z; acc10[0][3] += a4 * b0.w;
            acc10[1][0] += a5 * b0.x; acc10[1][1] += a5 * b0.y; acc10[1][2] += a5 * b0.z; acc10[1][3] += a5 * b0.w;
            acc10[2][0] += a6 * b0.x; acc10[2][1] += a6 * b0.y; acc10[2][2] += a6 * b0.z; acc10[2][3] += a6 * b0.w;
            acc10[3][0] += a7 * b0.x; acc10[3][1] += a7 * b0.y; acc10[3][2] += a7 * b0.z; acc10[3][3] += a7 * b0.w;
            acc11[0][0] += a4 * b1.x; acc11[0][1] += a4 * b1.y; acc11[0][2] += a4 * b1.z; acc11[0][3] += a4 * b1.w;
            acc11[1][0] += a5 * b1.x; acc11[1][1] += a5 * b1.y; acc11[1][2] += a5 * b1.z; acc11[1][3] += a5 * b1.w;
            acc11[2][0] += a6 * b1.x; acc11[2][1] += a6 * b1.y; acc11[2][2] += a6 * b1.z; acc11[2][3] += a6 * b1.w;
            acc11[3][0] += a7 * b1.x; acc11[3][1] += a7 * b1.y; acc11[3][2] += a7 * b1.z; acc11[3][3] += a7 * b1.w;
        }
        __syncthreads();
    }

    float4 bb0 = *reinterpret_cast<const float4*>(&bias[tx * 4]);
    float4 bb1 = *reinterpret_cast<const float4*>(&bias[64 + tx * 4]);
#pragma unroll
    for (int i = 0; i < 4; i++) {
        int gr0 = rb + ty * 4 + i;
        if (gr0 < N_NODES) {
            float4 o;
            o.x = acc00[i][0] + bb0.x; o.y = acc00[i][1] + bb0.y;
            o.z = acc00[i][2] + bb0.z; o.w = acc00[i][3] + bb0.w;
            *reinterpret_cast<float4*>(&out[gr0 * HC + tx * 4]) = o;
            o.x = acc01[i][0] + bb1.x; o.y = acc01[i][1] + bb1.y;
            o.z = acc01[i][2] + bb1.z; o.w = acc01[i][3] + bb1.w;
            *reinterpret_cast<float4*>(&out[gr0 * HC + 64 + tx * 4]) = o;
        }
        int gr1 = rb + 64 + ty * 4 + i;
        if (gr1 < N_NODES) {
            float4 o;
            o.x = acc10[i][0] + bb0.x; o.y = acc10[i][1] + bb0.y;
            o.z = acc10[i][2] + bb0.z; o.w = acc10[i][3] + bb0.w;
            *reinterpret_cast<float4*>(&out[gr1 * HC + tx * 4]) = o;
            o.x = acc11[i][0] + bb1.x; o.y = acc11[i][1] + bb1.y;
            o.z = acc11[i][2] + bb1.z; o.w = acc11[i][3] + bb1.w;
            *reinterpret_cast<float4*>(&out[gr1 * HC + 64 + tx * 4]) = o;
        }
    }
}

// ---------------- Fused GAT: 2 edges/wave, float4 lanes, direct-exp, 8 chains ----------------
// (r8 kernel, unchanged — at the gather roofline for this layout)

__device__ __forceinline__ float score4(float4 xl, float4 xr, float4 a) {
    float hx = xl.x + xr.x, hy = xl.y + xr.y, hz = xl.z + xr.z, hw = xl.w + xr.w;
    hx = fmaxf(hx, NEG_SLOPE * hx);
    hy = fmaxf(hy, NEG_SLOPE * hy);
    hz = fmaxf(hz, NEG_SLOPE * hz);
    hw = fmaxf(hw, NEG_SLOPE * hw);
    float c = ((a.x * hx + a.y * hy) + (a.z * hz + a.w * hw));
    c += __shfl_xor(c, 1);
    c += __shfl_xor(c, 2);
    c += __shfl_xor(c, 4);     // 8-lane head group holds e_h * log2e
    return fminf(c, 120.f);    // overflow insurance
}

__device__ __forceinline__ void upd4(float c, float4 xl, float& z, float4& acc) {
    float w = exp2f(c);
    z += w;
    acc.x += w * xl.x;
    acc.y += w * xl.y;
    acc.z += w * xl.z;
    acc.w += w * xl.w;
}

__global__ __launch_bounds__(256) void gat_fused_kernel(const float* __restrict__ XL,
    const float* __restrict__ XR, const float* __restrict__ att,
    const int* __restrict__ rowStart, const int* __restrict__ srcOff,
    const float* __restrict__ bvec, float* __restrict__ out, int applyElu) {
    int wv = threadIdx.x >> 6;
    int l = threadIdx.x & 63;
    int half = l >> 5;
    int cb = l & 31;
    int n = blockIdx.x * 4 + wv;
    if (n >= N_NODES) return;
    int s0 = rowStart[n], s1 = rowStart[n + 1];

    float4 xr4 = *reinterpret_cast<const float4*>(&XR[n * HC + 4 * cb]);
    float4 a4  = *reinterpret_cast<const float4*>(&att[4 * cb]);
    a4.x *= LOG2E; a4.y *= LOG2E; a4.z *= LOG2E; a4.w *= LOG2E;
    const char* XLb = reinterpret_cast<const char*>(XL) + 16 * cb;

    float z = 0.f;
    float4 acc = make_float4(0.f, 0.f, 0.f, 0.f);

    int p = s0;
    for (; p + 16 <= s1; p += 16) {
        int oA = srcOff[p      + half];
        int oB = srcOff[p + 2  + half];
        int oC = srcOff[p + 4  + half];
        int oD = srcOff[p + 6  + half];
        int oE = srcOff[p + 8  + half];
        int oF = srcOff[p + 10 + half];
        int oG = srcOff[p + 12 + half];
        int oH = srcOff[p + 14 + half];
        float4 xlA = *reinterpret_cast<const float4*>(XLb + (size_t)oA);
        float4 xlB = *reinterpret_cast<const float4*>(XLb + (size_t)oB);
        float4 xlC = *reinterpret_cast<const float4*>(XLb + (size_t)oC);
        float4 xlD = *reinterpret_cast<const float4*>(XLb + (size_t)oD);
        float4 xlE = *reinterpret_cast<const float4*>(XLb + (size_t)oE);
        float4 xlF = *reinterpret_cast<const float4*>(XLb + (size_t)oF);
        float4 xlG = *reinterpret_cast<const float4*>(XLb + (size_t)oG);
        float4 xlH = *reinterpret_cast<const float4*>(XLb + (size_t)oH);
        float cA = score4(xlA, xr4, a4);
        float cB = score4(xlB, xr4, a4);
        float cC = score4(xlC, xr4, a4);
        float cD = score4(xlD, xr4, a4);
        upd4(cA, xlA, z, acc);
        upd4(cB, xlB, z, acc);
        upd4(cC, xlC, z, acc);
        upd4(cD, xlD, z, acc);
        float cE = score4(xlE, xr4, a4);
        float cF = score4(xlF, xr4, a4);
        float cG = score4(xlG, xr4, a4);
        float cH = score4(xlH, xr4, a4);
        upd4(cE, xlE, z, acc);
        upd4(cF, xlF, z, acc);
        upd4(cG, xlG, z, acc);
        upd4(cH, xlH, z, acc);
    }
    for (; p + 8 <= s1; p += 8) {
        int oA = srcOff[p     + half];
        int oB = srcOff[p + 2 + half];
        int oC = srcOff[p + 4 + half];
        int oD = srcOff[p + 6 + half];
        float4 xlA = *reinterpret_cast<const float4*>(XLb + (size_t)oA);
        float4 xlB = *reinterpret_cast<const float4*>(XLb + (size_t)oB);
        float4 xlC = *reinterpret_cast<const float4*>(XLb + (size_t)oC);
        float4 xlD = *reinterpret_cast<const float4*>(XLb + (size_t)oD);
        float cA = score4(xlA, xr4, a4);
        float cB = score4(xlB, xr4, a4);
        float cC = score4(xlC, xr4, a4);
        float cD = score4(xlD, xr4, a4);
        upd4(cA, xlA, z, acc);
        upd4(cB, xlB, z, acc);
        upd4(cC, xlC, z, acc);
        upd4(cD, xlD, z, acc);
    }
    for (; p + 2 <= s1; p += 2) {
        int o = srcOff[p + half];
        float4 xl4 = *reinterpret_cast<const float4*>(XLb + (size_t)o);
        float c = score4(xl4, xr4, a4);
        upd4(c, xl4, z, acc);
    }
    if (p < s1) {
        int o = srcOff[p];
        float4 xl4 = *reinterpret_cast<const float4*>(XLb + (size_t)o);
        float c = score4(xl4, xr4, a4);
        if (half) c = NEGBIG;
        upd4(c, xl4, z, acc);
    }

    z     += __shfl_xor(z, 32);
    acc.x += __shfl_xor(acc.x, 32);
    acc.y += __shfl_xor(acc.y, 32);
    acc.z += __shfl_xor(acc.z, 32);
    acc.w += __shfl_xor(acc.w, 32);

    if (half == 0) {
        float zinv = 1.f / z;
        float4 b4 = *reinterpret_cast<const float4*>(&bvec[4 * cb]);
        float4 o4;
        o4.x = acc.x * zinv + b4.x;
        o4.y = acc.y * zinv + b4.y;
        o4.z = acc.z * zinv + b4.z;
        o4.w = acc.w * zinv + b4.w;
        if (applyElu) {
            o4.x = o4.x > 0.f ? o4.x : (__expf(o4.x) - 1.f);
            o4.y = o4.y > 0.f ? o4.y : (__expf(o4.y) - 1.f);
            o4.z = o4.z > 0.f ? o4.z : (__expf(o4.z) - 1.f);
            o4.w = o4.w > 0.f ? o4.w : (__expf(o4.w) - 1.f);
        }
        *reinterpret_cast<float4*>(&out[n * HC + 4 * cb]) = o4;
    }
}

// ---------------- launch ----------------

extern "C" void kernel_launch(void* const* d_in, const int* in_sizes, int n_in,
                              void* d_out, int out_size, void* d_ws, size_t ws_size,
                              hipStream_t stream) {
    const float* x = (const float*)d_in[0];
    const int* ei = (const int*)d_in[1];
    const int* srcArr = ei;
    const int* dstArr = ei + N_EDGES;

    char* ws = (char*)d_ws;
    size_t off = 0;
    auto alloc = [&](size_t bytes) -> void* {
        void* p = ws + off;
        off = (off + bytes + 511) & ~(size_t)511;
        return p;
    };
    float* P       = (float*)alloc((size_t)N_NODES * HC * 4);
    float* XL      = (float*)alloc((size_t)N_NODES * HC * 4);
    float* XR      = (float*)alloc((size_t)N_NODES * HC * 4);
    int* deg       = (int*)alloc((size_t)N_NODES * 4);
    int* rowStart  = (int*)alloc((size_t)(N_NODES + 1) * 4);
    int* blockSum  = (int*)alloc(64 * 4);
    int* blockOff  = (int*)alloc(64 * 4);
    int* bucketCur = (int*)alloc((size_t)NBUCKETS * 4);
    int* E         = (int*)alloc((size_t)ETOT * 4);
    int* srcOff    = (int*)alloc((size_t)ETOT * 4);

    const int NSCAN = (N_NODES + 1023) / 1024;   // 49

    hipMemsetAsync(deg, 0, (size_t)N_NODES * 4, stream);
    hist_kernel<<<(ETOT + 255) / 256, 256, 0, stream>>>(dstArr, deg);
    scanA_kernel<<<NSCAN, 1024, 0, stream>>>(deg, rowStart, blockSum);
    scanB_kernel<<<1, 64, 0, stream>>>(blockSum, blockOff, NSCAN);
    scanC_kernel<<<NSCAN, 1024, 0, stream>>>(rowStart, blockOff, bucketCur);
    chunk_scatter_kernel<<<NCHUNK, 256, 0, stream>>>(srcArr, dstArr, bucketCur, E);
    csr_scatter_kernel<<<NBUCKETS, 256, 0, stream>>>(E, rowStart, srcOff);

    for (int lyr = 0; lyr < 3; lyr++) {
        const float* xin = (lyr == 0) ? x : P;
        float* xout = (lyr == 2) ? (float*)d_out : P;
        const float* Wl  = (const float*)d_in[2 + 6 * lyr + 0];
        const float* bl  = (const float*)d_in[2 + 6 * lyr + 1];
        const float* Wr  = (const float*)d_in[2 + 6 * lyr + 2];
        const float* br  = (const float*)d_in[2 + 6 * lyr + 3];
        const float* att = (const float*)d_in[2 + 6 * lyr + 4];
        const float* bb  = (const float*)d_in[2 + 6 * lyr + 5];

        dim3 ggrid((N_NODES + 127) / 128, 2);
        gemm_kernel<<<ggrid, 256, 0, stream>>>(xin, Wl, bl, Wr, br, XL, XR);

        int nb = (N_NODES + 3) / 4;
        gat_fused_kernel<<<nb, 256, 0, stream>>>(XL, XR, att, rowStart, srcOff, bb, xout, lyr < 2 ? 1 : 0);
    }
}

// Round 11
// 472.987 us; speedup vs baseline: 1.2794x; 1.2628x over previous
//
#include <hip/hip_runtime.h>
#include <hip/hip_fp16.h>
#include <math.h>

#define N_NODES 50000
#define N_EDGES 1600000
#define ETOT (N_EDGES + N_NODES)
#define HC 128
#define HEADS 4
#define HID 32
#define NEG_SLOPE 0.2f
#define NPB 32                               // nodes per bucket (aligned)
#define NBUCKETS ((N_NODES + NPB - 1) / NPB) // 1563
#define CHUNK 8192
#define NCHUNK ((ETOT + CHUNK - 1) / CHUNK)  // 202
#define LOG2E 1.4426950408889634f
#define NEGBIG (-1e30f)

// ---------------- CSR build ----------------

__global__ __launch_bounds__(256) void hist_kernel(const int* __restrict__ dstArr, int* __restrict__ deg) {
    int i = blockIdx.x * 256 + threadIdx.x;
    if (i >= ETOT) return;
    int d = (i < N_EDGES) ? dstArr[i] : (i - N_EDGES);
    atomicAdd(&deg[d], 1);
}

__global__ __launch_bounds__(1024) void scanA_kernel(const int* __restrict__ deg,
                                                     int* __restrict__ rowStart, int* __restrict__ blockSum) {
    __shared__ int buf[1024];
    int i = blockIdx.x * 1024 + threadIdx.x;
    int v = (i < N_NODES) ? deg[i] : 0;
    buf[threadIdx.x] = v;
    __syncthreads();
    for (int off = 1; off < 1024; off <<= 1) {
        int t = (threadIdx.x >= off) ? buf[threadIdx.x - off] : 0;
        __syncthreads();
        buf[threadIdx.x] += t;
        __syncthreads();
    }
    if (i < N_NODES) rowStart[i] = buf[threadIdx.x] - v;   // exclusive, pre-offset
    if (threadIdx.x == 1023) blockSum[blockIdx.x] = buf[1023];
}

__global__ void scanB_kernel(const int* __restrict__ blockSum, int* __restrict__ blockOff, int nb) {
    if (threadIdx.x == 0 && blockIdx.x == 0) {
        int acc = 0;
        for (int j = 0; j < nb; j++) { blockOff[j] = acc; acc += blockSum[j]; }
    }
}

// adds block offsets; also emits bucket cursors (rowStart[b*32]) and the sentinel
__global__ __launch_bounds__(1024) void scanC_kernel(int* __restrict__ rowStart, const int* __restrict__ blockOff,
                                                     int* __restrict__ bucketCursor) {
    int i = blockIdx.x * 1024 + threadIdx.x;
    if (i < N_NODES) {
        int v = rowStart[i] + blockOff[blockIdx.x];
        rowStart[i] = v;
        if ((i & (NPB - 1)) == 0) bucketCursor[i >> 5] = v;
    }
    if (i == 0) rowStart[N_NODES] = ETOT;   // sentinel
}

// Pass 1: chunked counting-sort scatter to bucket granularity.
__global__ __launch_bounds__(256) void chunk_scatter_kernel(const int* __restrict__ srcArr, const int* __restrict__ dstArr,
                                                            int* __restrict__ bucketCursor, int* __restrict__ E) {
    __shared__ int hist[NBUCKETS];   // then reused as running cursor
    int c0 = blockIdx.x * CHUNK;
    int c1 = min(c0 + CHUNK, ETOT);
    for (int b = threadIdx.x; b < NBUCKETS; b += 256) hist[b] = 0;
    __syncthreads();

    int myP[CHUNK / 256];   // packed src | (d<<16)
    int cnt = 0;
    for (int i = c0 + threadIdx.x; i < c1; i += 256) {
        int s, d;
        if (i < N_EDGES) { s = srcArr[i]; d = dstArr[i]; }
        else             { s = i - N_EDGES; d = s; }
        myP[cnt] = s | (d << 16);
        cnt++;
        atomicAdd(&hist[d >> 5], 1);
    }
    __syncthreads();
    for (int b = threadIdx.x; b < NBUCKETS; b += 256) {
        int h = hist[b];
        hist[b] = (h > 0) ? atomicAdd(&bucketCursor[b], h) : 0;
    }
    __syncthreads();
    for (int k = 0; k < cnt; k++) {
        int pe = myP[k];
        int pos = atomicAdd(&hist[((unsigned)pe) >> 21], 1);   // bucket = d>>5
        E[pos] = pe;
    }
}

// Pass 2: one block per bucket; emits BYTE offsets src*256 into srcOff (fp16 rows)
__global__ __launch_bounds__(256) void csr_scatter_kernel(const int* __restrict__ E, const int* __restrict__ rowStart,
                                                          int* __restrict__ srcOff) {
    __shared__ int lcur[NPB];
    int b = blockIdx.x;
    int n0 = b * NPB;
    int nend = min(n0 + NPB, N_NODES);
    if (threadIdx.x < nend - n0) lcur[threadIdx.x] = rowStart[n0 + threadIdx.x];
    __syncthreads();
    int e0 = rowStart[n0];
    int e1 = rowStart[nend];
    for (int i = e0 + threadIdx.x; i < e1; i += 256) {
        int pe = E[i];
        int pos = atomicAdd(&lcur[(pe >> 16) & (NPB - 1)], 1);
        srcOff[pos] = (pe & 0xFFFF) << 8;     // byte offset into XLh (row = 256 B fp16)
    }
}

// ---------------- GEMM: 128x128 tile, 8x8 per thread, K-step 32 ----------------
// grid = (ceil(N/128), 2); y=0: XLh (fp16) = x@Wl+bl, y=1: XR (fp32) = x@Wr+br.

__global__ __launch_bounds__(256) void gemm_kernel(const float* __restrict__ x,
    const float* __restrict__ Wl, const float* __restrict__ bl,
    const float* __restrict__ Wr, const float* __restrict__ br,
    __half* __restrict__ XLh, float* __restrict__ XR) {
    __shared__ float As[128][36];
    __shared__ float Bs[32][128];
    int t = threadIdx.x;
    int rb = blockIdx.x * 128;
    int isXL = (blockIdx.y == 0);
    const float* W    = isXL ? Wl : Wr;
    const float* bias = isXL ? bl : br;
    int tx = t & 15, ty = t >> 4;

    float acc00[4][4], acc01[4][4], acc10[4][4], acc11[4][4];
#pragma unroll
    for (int i = 0; i < 4; i++)
#pragma unroll
        for (int j = 0; j < 4; j++) { acc00[i][j] = 0.f; acc01[i][j] = 0.f; acc10[i][j] = 0.f; acc11[i][j] = 0.f; }

    for (int kt = 0; kt < 4; kt++) {
#pragma unroll
        for (int it = 0; it < 4; it++) {
            int idx = it * 256 + t;
            int r = idx >> 3, f = idx & 7;
            int gr = rb + r;
            float4 v = make_float4(0.f, 0.f, 0.f, 0.f);
            if (gr < N_NODES) v = *reinterpret_cast<const float4*>(&x[gr * HC + kt * 32 + f * 4]);
            *reinterpret_cast<float4*>(&As[r][f * 4]) = v;
        }
#pragma unroll
        for (int it = 0; it < 4; it++) {
            int idx = it * 256 + t;
            int k = idx >> 5, f = idx & 31;
            *reinterpret_cast<float4*>(&Bs[k][f * 4]) =
                *reinterpret_cast<const float4*>(&W[(kt * 32 + k) * HC + f * 4]);
        }
        __syncthreads();
#pragma unroll 4
        for (int k = 0; k < 32; k++) {
            float4 b0 = *reinterpret_cast<const float4*>(&Bs[k][tx * 4]);
            float4 b1 = *reinterpret_cast<const float4*>(&Bs[k][64 + tx * 4]);
            float a0 = As[ty * 4 + 0][k];
            float a1 = As[ty * 4 + 1][k];
            float a2 = As[ty * 4 + 2][k];
            float a3 = As[ty * 4 + 3][k];
            float a4 = As[64 + ty * 4 + 0][k];
            float a5 = As[64 + ty * 4 + 1][k];
            float a6 = As[64 + ty * 4 + 2][k];
            float a7 = As[64 + ty * 4 + 3][k];
            acc00[0][0] += a0 * b0.x; acc00[0][1] += a0 * b0.y; acc00[0][2] += a0 * b0.z; acc00[0][3] += a0 * b0.w;
            acc00[1][0] += a1 * b0.x; acc00[1][1] += a1 * b0.y; acc00[1][2] += a1 * b0.z; acc00[1][3] += a1 * b0.w;
            acc00[2][0] += a2 * b0.x; acc00[2][1] += a2 * b0.y; acc00[2][2] += a2 * b0.z; acc00[2][3] += a2 * b0.w;
            acc00[3][0] += a3 * b0.x; acc00[3][1] += a3 * b0.y; acc00[3][2] += a3 * b0.z; acc00[3][3] += a3 * b0.w;
            acc01[0][0] += a0 * b1.x; acc01[0][1] += a0 * b1.y; acc01[0][2] += a0 * b1.z; acc01[0][3] += a0 * b1.w;
            acc01[1][0] += a1 * b1.x; acc01[1][1] += a1 * b1.y; acc01[1][2] += a1 * b1.z; acc01[1][3] += a1 * b1.w;
            acc01[2][0] += a2 * b1.x; acc01[2][1] += a2 * b1.y; acc01[2][2] += a2 * b1.z; acc01[2][3] += a2 * b1.w;
            acc01[3][0] += a3 * b1.x; acc01[3][1] += a3 * b1.y; acc01[3][2] += a3 * b1.z; acc01[3][3] += a3 * b1.w;
            acc10[0][0] += a4 * b0.x; acc10[0][1] += a4 * b0.y; acc10[0][2] += a4 * b0.z; acc10[0][3] += a4 * b0.w;
            acc10[1][0] += a5 * b0.x; acc10[1][1] += a5 * b0.y; acc10[1][2] += a5 * b0.z; acc10[1][3] += a5 * b0.w;
            acc10[2][0] += a6 * b0.x; acc10[2][1] += a6 * b0.y; acc10[2][2] += a6 * b0.z; acc10[2][3] += a6 * b0.w;
            acc10[3][0] += a7 * b0.x; acc10[3][1] += a7 * b0.y; acc10[3][2] += a7 * b0.z; acc10[3][3] += a7 * b0.w;
            acc11[0][0] += a4 * b1.x; acc11[0][1] += a4 * b1.y; acc11[0][2] += a4 * b1.z; acc11[0][3] += a4 * b1.w;
            acc11[1][0] += a5 * b1.x; acc11[1][1] += a5 * b1.y; acc11[1][2] += a5 * b1.z; acc11[1][3] += a5 * b1.w;
            acc11[2][0] += a6 * b1.x; acc11[2][1] += a6 * b1.y; acc11[2][2] += a6 * b1.z; acc11[2][3] += a6 * b1.w;
            acc11[3][0] += a7 * b1.x; acc11[3][1] += a7 * b1.y; acc11[3][2] += a7 * b1.z; acc11[3][3] += a7 * b1.w;
        }
        __syncthreads();
    }

    float4 bb0 = *reinterpret_cast<const float4*>(&bias[tx * 4]);
    float4 bb1 = *reinterpret_cast<const float4*>(&bias[64 + tx * 4]);
#pragma unroll
    for (int i = 0; i < 4; i++) {
        int gr0 = rb + ty * 4 + i;
        int gr1 = rb + 64 + ty * 4 + i;
        float4 o00, o01, o10, o11;
        o00.x = acc00[i][0] + bb0.x; o00.y = acc00[i][1] + bb0.y; o00.z = acc00[i][2] + bb0.z; o00.w = acc00[i][3] + bb0.w;
        o01.x = acc01[i][0] + bb1.x; o01.y = acc01[i][1] + bb1.y; o01.z = acc01[i][2] + bb1.z; o01.w = acc01[i][3] + bb1.w;
        o10.x = acc10[i][0] + bb0.x; o10.y = acc10[i][1] + bb0.y; o10.z = acc10[i][2] + bb0.z; o10.w = acc10[i][3] + bb0.w;
        o11.x = acc11[i][0] + bb1.x; o11.y = acc11[i][1] + bb1.y; o11.z = acc11[i][2] + bb1.z; o11.w = acc11[i][3] + bb1.w;
        if (isXL) {
            if (gr0 < N_NODES) {
                ushort4 s0, s1;
                s0.x = __half_as_ushort(__float2half(o00.x)); s0.y = __half_as_ushort(__float2half(o00.y));
                s0.z = __half_as_ushort(__float2half(o00.z)); s0.w = __half_as_ushort(__float2half(o00.w));
                s1.x = __half_as_ushort(__float2half(o01.x)); s1.y = __half_as_ushort(__float2half(o01.y));
                s1.z = __half_as_ushort(__float2half(o01.z)); s1.w = __half_as_ushort(__float2half(o01.w));
                *reinterpret_cast<ushort4*>(&XLh[gr0 * HC + tx * 4]) = s0;
                *reinterpret_cast<ushort4*>(&XLh[gr0 * HC + 64 + tx * 4]) = s1;
            }
            if (gr1 < N_NODES) {
                ushort4 s0, s1;
                s0.x = __half_as_ushort(__float2half(o10.x)); s0.y = __half_as_ushort(__float2half(o10.y));
                s0.z = __half_as_ushort(__float2half(o10.z)); s0.w = __half_as_ushort(__float2half(o10.w));
                s1.x = __half_as_ushort(__float2half(o11.x)); s1.y = __half_as_ushort(__float2half(o11.y));
                s1.z = __half_as_ushort(__float2half(o11.z)); s1.w = __half_as_ushort(__float2half(o11.w));
                *reinterpret_cast<ushort4*>(&XLh[gr1 * HC + tx * 4]) = s0;
                *reinterpret_cast<ushort4*>(&XLh[gr1 * HC + 64 + tx * 4]) = s1;
            }
        } else {
            if (gr0 < N_NODES) {
                *reinterpret_cast<float4*>(&XR[gr0 * HC + tx * 4]) = o00;
                *reinterpret_cast<float4*>(&XR[gr0 * HC + 64 + tx * 4]) = o01;
            }
            if (gr1 < N_NODES) {
                *reinterpret_cast<float4*>(&XR[gr1 * HC + tx * 4]) = o10;
                *reinterpret_cast<float4*>(&XR[gr1 * HC + 64 + tx * 4]) = o11;
            }
        }
    }
}

// ---------------- Fused GAT: fp16 XL, 4 edges/wave, 16 lanes/edge ----------------
// Lane l: q = l>>4 = edge slot (0..3); cl = l&15 covers channels [8cl, 8cl+8).
// Head = cl>>2 (4 lanes x 8 ch = 32 ch). Scores in log2 domain (att pre-scaled).
// Direct-exp softmax (scores O(10), clamp 120); z-normalization exact.

struct F8 { float v[8]; };

__device__ __forceinline__ F8 loadXL8(const char* XLb, int o) {
    uint4 ld = *reinterpret_cast<const uint4*>(XLb + (size_t)(unsigned)o);
    F8 r;
    __half2 h0 = *reinterpret_cast<__half2*>(&ld.x);
    __half2 h1 = *reinterpret_cast<__half2*>(&ld.y);
    __half2 h2 = *reinterpret_cast<__half2*>(&ld.z);
    __half2 h3 = *reinterpret_cast<__half2*>(&ld.w);
    float2 f0 = __half22float2(h0);
    float2 f1 = __half22float2(h1);
    float2 f2 = __half22float2(h2);
    float2 f3 = __half22float2(h3);
    r.v[0] = f0.x; r.v[1] = f0.y; r.v[2] = f1.x; r.v[3] = f1.y;
    r.v[4] = f2.x; r.v[5] = f2.y; r.v[6] = f3.x; r.v[7] = f3.y;
    return r;
}

__device__ __forceinline__ float score8(const F8& xl, const float* xr, const float* a) {
    float c = 0.f;
#pragma unroll
    for (int i = 0; i < 8; i++) {
        float h = xl.v[i] + xr[i];
        h = fmaxf(h, NEG_SLOPE * h);
        c = fmaf(a[i], h, c);
    }
    c += __shfl_xor(c, 1);
    c += __shfl_xor(c, 2);          // 4-lane head group holds e_h * log2e
    return fminf(c, 120.f);
}

__device__ __forceinline__ void upd8(float c, const F8& xl, float& z, float* acc) {
    float w = exp2f(c);
    z += w;
#pragma unroll
    for (int i = 0; i < 8; i++) acc[i] = fmaf(w, xl.v[i], acc[i]);
}

__global__ __launch_bounds__(256) void gat_fused_kernel(const __half* __restrict__ XLh,
    const float* __restrict__ XR, const float* __restrict__ att,
    const int* __restrict__ rowStart, const int* __restrict__ srcOff,
    const float* __restrict__ bvec, float* __restrict__ out, int applyElu) {
    int wv = threadIdx.x >> 6;
    int l = threadIdx.x & 63;
    int q = l >> 4;
    int cl = l & 15;
    int n = blockIdx.x * 4 + wv;
    if (n >= N_NODES) return;
    int s0 = rowStart[n], s1 = rowStart[n + 1];

    float xr[8], a[8];
    {
        float4 x0 = *reinterpret_cast<const float4*>(&XR[n * HC + 8 * cl]);
        float4 x1 = *reinterpret_cast<const float4*>(&XR[n * HC + 8 * cl + 4]);
        float4 a0 = *reinterpret_cast<const float4*>(&att[8 * cl]);
        float4 a1 = *reinterpret_cast<const float4*>(&att[8 * cl + 4]);
        xr[0] = x0.x; xr[1] = x0.y; xr[2] = x0.z; xr[3] = x0.w;
        xr[4] = x1.x; xr[5] = x1.y; xr[6] = x1.z; xr[7] = x1.w;
        a[0] = a0.x * LOG2E; a[1] = a0.y * LOG2E; a[2] = a0.z * LOG2E; a[3] = a0.w * LOG2E;
        a[4] = a1.x * LOG2E; a[5] = a1.y * LOG2E; a[6] = a1.z * LOG2E; a[7] = a1.w * LOG2E;
    }
    const char* XLb = reinterpret_cast<const char*>(XLh) + 16 * cl;

    float z = 0.f;
    float acc[8];
#pragma unroll
    for (int i = 0; i < 8; i++) acc[i] = 0.f;

    int p = s0;
    // 16 edges per iteration: 4 gather instructions, each serving 4 edges
    for (; p + 16 <= s1; p += 16) {
        int oA = srcOff[p      + q];
        int oB = srcOff[p + 4  + q];
        int oC = srcOff[p + 8  + q];
        int oD = srcOff[p + 12 + q];
        F8 xA = loadXL8(XLb, oA);
        F8 xB = loadXL8(XLb, oB);
        F8 xC = loadXL8(XLb, oC);
        F8 xD = loadXL8(XLb, oD);
        float cA = score8(xA, xr, a);
        float cB = score8(xB, xr, a);
        float cC = score8(xC, xr, a);
        float cD = score8(xD, xr, a);
        upd8(cA, xA, z, acc);
        upd8(cB, xB, z, acc);
        upd8(cC, xC, z, acc);
        upd8(cD, xD, z, acc);
    }
    for (; p + 4 <= s1; p += 4) {
        int o = srcOff[p + q];
        F8 x = loadXL8(XLb, o);
        float c = score8(x, xr, a);
        upd8(c, x, z, acc);
    }
    if (p < s1) {
        int r = s1 - p;                         // 1..3 remaining
        int o = srcOff[min(p + q, s1 - 1)];     // clamped (no OOB), poisoned below
        F8 x = loadXL8(XLb, o);
        float c = score8(x, xr, a);
        if (q >= r) c = NEGBIG;                 // exp2 -> 0, contributes nothing
        upd8(c, x, z, acc);
    }

    // merge the 4 edge-slot partial sums (lanes 16/32 apart)
    z += __shfl_xor(z, 16);
    z += __shfl_xor(z, 32);
#pragma unroll
    for (int i = 0; i < 8; i++) {
        acc[i] += __shfl_xor(acc[i], 16);
        acc[i] += __shfl_xor(acc[i], 32);
    }

    if (q == 0) {
        float zinv = 1.f / z;
        float4 b0 = *reinterpret_cast<const float4*>(&bvec[8 * cl]);
        float4 b1 = *reinterpret_cast<const float4*>(&bvec[8 * cl + 4]);
        float o0[8];
        o0[0] = acc[0] * zinv + b0.x; o0[1] = acc[1] * zinv + b0.y;
        o0[2] = acc[2] * zinv + b0.z; o0[3] = acc[3] * zinv + b0.w;
        o0[4] = acc[4] * zinv + b1.x; o0[5] = acc[5] * zinv + b1.y;
        o0[6] = acc[6] * zinv + b1.z; o0[7] = acc[7] * zinv + b1.w;
        if (applyElu) {
#pragma unroll
            for (int i = 0; i < 8; i++) o0[i] = o0[i] > 0.f ? o0[i] : (__expf(o0[i]) - 1.f);
        }
        float4 w0 = make_float4(o0[0], o0[1], o0[2], o0[3]);
        float4 w1 = make_float4(o0[4], o0[5], o0[6], o0[7]);
        *reinterpret_cast<float4*>(&out[n * HC + 8 * cl]) = w0;
        *reinterpret_cast<float4*>(&out[n * HC + 8 * cl + 4]) = w1;
    }
}

// ---------------- launch ----------------

extern "C" void kernel_launch(void* const* d_in, const int* in_sizes, int n_in,
                              void* d_out, int out_size, void* d_ws, size_t ws_size,
                              hipStream_t stream) {
    const float* x = (const float*)d_in[0];
    const int* ei = (const int*)d_in[1];
    const int* srcArr = ei;
    const int* dstArr = ei + N_EDGES;

    char* ws = (char*)d_ws;
    size_t off = 0;
    auto alloc = [&](size_t bytes) -> void* {
        void* p = ws + off;
        off = (off + bytes + 511) & ~(size_t)511;
        return p;
    };
    float* P       = (float*)alloc((size_t)N_NODES * HC * 4);
    __half* XLh    = (__half*)alloc((size_t)N_NODES * HC * 2);
    float* XR      = (float*)alloc((size_t)N_NODES * HC * 4);
    int* deg       = (int*)alloc((size_t)N_NODES * 4);
    int* rowStart  = (int*)alloc((size_t)(N_NODES + 1) * 4);
    int* blockSum  = (int*)alloc(64 * 4);
    int* blockOff  = (int*)alloc(64 * 4);
    int* bucketCur = (int*)alloc((size_t)NBUCKETS * 4);
    int* E         = (int*)alloc((size_t)ETOT * 4);
    int* srcOff    = (int*)alloc((size_t)ETOT * 4);

    const int NSCAN = (N_NODES + 1023) / 1024;   // 49

    hipMemsetAsync(deg, 0, (size_t)N_NODES * 4, stream);
    hist_kernel<<<(ETOT + 255) / 256, 256, 0, stream>>>(dstArr, deg);
    scanA_kernel<<<NSCAN, 1024, 0, stream>>>(deg, rowStart, blockSum);
    scanB_kernel<<<1, 64, 0, stream>>>(blockSum, blockOff, NSCAN);
    scanC_kernel<<<NSCAN, 1024, 0, stream>>>(rowStart, blockOff, bucketCur);
    chunk_scatter_kernel<<<NCHUNK, 256, 0, stream>>>(srcArr, dstArr, bucketCur, E);
    csr_scatter_kernel<<<NBUCKETS, 256, 0, stream>>>(E, rowStart, srcOff);

    for (int lyr = 0; lyr < 3; lyr++) {
        const float* xin = (lyr == 0) ? x : P;
        float* xout = (lyr == 2) ? (float*)d_out : P;
        const float* Wl  = (const float*)d_in[2 + 6 * lyr + 0];
        const float* bl  = (const float*)d_in[2 + 6 * lyr + 1];
        const float* Wr  = (const float*)d_in[2 + 6 * lyr + 2];
        const float* br  = (const float*)d_in[2 + 6 * lyr + 3];
        const float* att = (const float*)d_in[2 + 6 * lyr + 4];
        const float* bb  = (const float*)d_in[2 + 6 * lyr + 5];

        dim3 ggrid((N_NODES + 127) / 128, 2);
        gemm_kernel<<<ggrid, 256, 0, stream>>>(xin, Wl, bl, Wr, br, XLh, XR);

        int nb = (N_NODES + 3) / 4;
        gat_fused_kernel<<<nb, 256, 0, stream>>>(XLh, XR, att, rowStart, srcOff, bb, xout, lyr < 2 ? 1 : 0);
    }
}

// Round 12
// 455.073 us; speedup vs baseline: 1.3298x; 1.0394x over previous
//
#include <hip/hip_runtime.h>
#include <hip/hip_fp16.h>
#include <math.h>

#define N_NODES 50000
#define N_EDGES 1600000
#define ETOT (N_EDGES + N_NODES)
#define HC 128
#define HEADS 4
#define HID 32
#define NEG_SLOPE 0.2f
#define NPB 32                               // nodes per bucket (aligned)
#define NBUCKETS ((N_NODES + NPB - 1) / NPB) // 1563
#define CHUNK 8192
#define NCHUNK ((ETOT + CHUNK - 1) / CHUNK)  // 202
#define LOG2E 1.4426950408889634f
#define NEGBIG (-1e30f)

typedef _Float16 h2 __attribute__((ext_vector_type(2)));

__device__ __forceinline__ unsigned pack2(float a, float b) {
    return ((unsigned)__half_as_ushort(__float2half(b)) << 16) | __half_as_ushort(__float2half(a));
}

__device__ __forceinline__ float fdot2u(unsigned a, unsigned b, float c) {
#if __has_builtin(__builtin_amdgcn_fdot2)
    return __builtin_amdgcn_fdot2(__builtin_bit_cast(h2, a), __builtin_bit_cast(h2, b), c, false);
#else
    __half2 ha = __builtin_bit_cast(__half2, a);
    __half2 hb = __builtin_bit_cast(__half2, b);
    float2 fa = __half22float2(ha), fb = __half22float2(hb);
    return fmaf(fa.x, fb.x, fmaf(fa.y, fb.y, c));
#endif
}

// ---------------- CSR build ----------------

__global__ __launch_bounds__(256) void hist_kernel(const int* __restrict__ dstArr, int* __restrict__ deg) {
    int i = blockIdx.x * 256 + threadIdx.x;
    if (i >= ETOT) return;
    int d = (i < N_EDGES) ? dstArr[i] : (i - N_EDGES);
    atomicAdd(&deg[d], 1);
}

__global__ __launch_bounds__(1024) void scanA_kernel(const int* __restrict__ deg,
                                                     int* __restrict__ rowStart, int* __restrict__ blockSum) {
    __shared__ int buf[1024];
    int i = blockIdx.x * 1024 + threadIdx.x;
    int v = (i < N_NODES) ? deg[i] : 0;
    buf[threadIdx.x] = v;
    __syncthreads();
    for (int off = 1; off < 1024; off <<= 1) {
        int t = (threadIdx.x >= off) ? buf[threadIdx.x - off] : 0;
        __syncthreads();
        buf[threadIdx.x] += t;
        __syncthreads();
    }
    if (i < N_NODES) rowStart[i] = buf[threadIdx.x] - v;   // exclusive, pre-offset
    if (threadIdx.x == 1023) blockSum[blockIdx.x] = buf[1023];
}

__global__ void scanB_kernel(const int* __restrict__ blockSum, int* __restrict__ blockOff, int nb) {
    if (threadIdx.x == 0 && blockIdx.x == 0) {
        int acc = 0;
        for (int j = 0; j < nb; j++) { blockOff[j] = acc; acc += blockSum[j]; }
    }
}

__global__ __launch_bounds__(1024) void scanC_kernel(int* __restrict__ rowStart, const int* __restrict__ blockOff,
                                                     int* __restrict__ bucketCursor) {
    int i = blockIdx.x * 1024 + threadIdx.x;
    if (i < N_NODES) {
        int v = rowStart[i] + blockOff[blockIdx.x];
        rowStart[i] = v;
        if ((i & (NPB - 1)) == 0) bucketCursor[i >> 5] = v;
    }
    if (i == 0) rowStart[N_NODES] = ETOT;   // sentinel
}

// Pass 1: chunked counting-sort scatter to bucket granularity.
__global__ __launch_bounds__(256) void chunk_scatter_kernel(const int* __restrict__ srcArr, const int* __restrict__ dstArr,
                                                            int* __restrict__ bucketCursor, int* __restrict__ E) {
    __shared__ int hist[NBUCKETS];   // then reused as running cursor
    int c0 = blockIdx.x * CHUNK;
    int c1 = min(c0 + CHUNK, ETOT);
    for (int b = threadIdx.x; b < NBUCKETS; b += 256) hist[b] = 0;
    __syncthreads();

    int myP[CHUNK / 256];   // packed src | (d<<16)
    int cnt = 0;
    for (int i = c0 + threadIdx.x; i < c1; i += 256) {
        int s, d;
        if (i < N_EDGES) { s = srcArr[i]; d = dstArr[i]; }
        else             { s = i - N_EDGES; d = s; }
        myP[cnt] = s | (d << 16);
        cnt++;
        atomicAdd(&hist[d >> 5], 1);
    }
    __syncthreads();
    for (int b = threadIdx.x; b < NBUCKETS; b += 256) {
        int h = hist[b];
        hist[b] = (h > 0) ? atomicAdd(&bucketCursor[b], h) : 0;
    }
    __syncthreads();
    for (int k = 0; k < cnt; k++) {
        int pe = myP[k];
        int pos = atomicAdd(&hist[((unsigned)pe) >> 21], 1);   // bucket = d>>5
        E[pos] = pe;
    }
}

// Pass 2: one block per bucket; emits BYTE offsets src*256 into srcOff (fp16 rows)
__global__ __launch_bounds__(256) void csr_scatter_kernel(const int* __restrict__ E, const int* __restrict__ rowStart,
                                                          int* __restrict__ srcOff) {
    __shared__ int lcur[NPB];
    int b = blockIdx.x;
    int n0 = b * NPB;
    int nend = min(n0 + NPB, N_NODES);
    if (threadIdx.x < nend - n0) lcur[threadIdx.x] = rowStart[n0 + threadIdx.x];
    __syncthreads();
    int e0 = rowStart[n0];
    int e1 = rowStart[nend];
    for (int i = e0 + threadIdx.x; i < e1; i += 256) {
        int pe = E[i];
        int pos = atomicAdd(&lcur[(pe >> 16) & (NPB - 1)], 1);
        srcOff[pos] = (pe & 0xFFFF) << 8;     // byte offset into XLh (row = 256 B fp16)
    }
}

// ---------------- fp16 prep: x -> xh, W -> k-interleaved half2 ----------------

__global__ __launch_bounds__(256) void cvt_x_kernel(const float* __restrict__ x, __half* __restrict__ xh) {
    int i = blockIdx.x * 256 + threadIdx.x;      // 8 halves per thread
    if (i >= N_NODES * HC / 8) return;
    const float4* s = reinterpret_cast<const float4*>(x + (size_t)i * 8);
    float4 v0 = s[0], v1 = s[1];
    uint4 o;
    o.x = pack2(v0.x, v0.y); o.y = pack2(v0.z, v0.w);
    o.z = pack2(v1.x, v1.y); o.w = pack2(v1.z, v1.w);
    reinterpret_cast<uint4*>(xh)[i] = o;
}

// Wp[mat][k2][n] = half2(W[2k2][n], W[2k2+1][n]);  mat 0=Wl 1=Wr
__global__ __launch_bounds__(256) void pack_w_kernel(const float* __restrict__ Wl, const float* __restrict__ Wr,
                                                     unsigned* __restrict__ Wp) {
    int i = blockIdx.x * 256 + threadIdx.x;      // 2*64*128 = 16384
    if (i >= 2 * 64 * HC) return;
    int mat = i >> 13;
    int k2 = (i >> 7) & 63;
    int n = i & 127;
    const float* W = mat ? Wr : Wl;
    Wp[i] = pack2(W[(2 * k2) * HC + n], W[(2 * k2 + 1) * HC + n]);
}

// ---------------- GEMM (fp16 dot2): 128x128 tile, 8x8/thread, K-step 32 ----------------
// grid = (ceil(N/128), 2); y=0: XLh (fp16) = in@Wl+bl, y=1: XR (fp32) = in@Wr+br.

__global__ __launch_bounds__(256) void gemm_kernel(const __half* __restrict__ xin,
    const unsigned* __restrict__ Wp, const float* __restrict__ bl, const float* __restrict__ br,
    __half* __restrict__ XLh, float* __restrict__ XR) {
    __shared__ unsigned As2[128][20];   // 16 half2 per row (+4 pad)
    __shared__ unsigned Bs2[16][132];   // [k2][n] half2 (+4 pad)
    int t = threadIdx.x;
    int rb = blockIdx.x * 128;
    int mat = blockIdx.y;
    const float* bias = mat ? br : bl;
    int tx = t & 15, ty = t >> 4;

    float acc00[4][4], acc01[4][4], acc10[4][4], acc11[4][4];
#pragma unroll
    for (int i = 0; i < 4; i++)
#pragma unroll
        for (int j = 0; j < 4; j++) { acc00[i][j] = 0.f; acc01[i][j] = 0.f; acc10[i][j] = 0.f; acc11[i][j] = 0.f; }

    for (int kt = 0; kt < 4; kt++) {
        // A tile: 128 rows x 32 k fp16 = 512 uint4
#pragma unroll
        for (int it = 0; it < 2; it++) {
            int idx = it * 256 + t;
            int r = idx >> 2, f = idx & 3;
            int gr = rb + r;
            uint4 v = make_uint4(0, 0, 0, 0);
            if (gr < N_NODES) v = *reinterpret_cast<const uint4*>(xin + (size_t)gr * HC + kt * 32 + f * 8);
            *reinterpret_cast<uint4*>(&As2[r][f * 4]) = v;
        }
        // B tile: 16 k2 x 128 n half2 = 512 uint4
#pragma unroll
        for (int it = 0; it < 2; it++) {
            int idx = it * 256 + t;
            int k2 = idx >> 5, f = idx & 31;
            *reinterpret_cast<uint4*>(&Bs2[k2][f * 4]) =
                *reinterpret_cast<const uint4*>(Wp + ((size_t)(mat * 64 + kt * 16 + k2) * HC + f * 4));
        }
        __syncthreads();
#pragma unroll
        for (int k2 = 0; k2 < 16; k2++) {
            uint4 bv0 = *reinterpret_cast<const uint4*>(&Bs2[k2][tx * 4]);
            uint4 bv1 = *reinterpret_cast<const uint4*>(&Bs2[k2][64 + tx * 4]);
            unsigned av[8];
#pragma unroll
            for (int i = 0; i < 4; i++) av[i] = As2[ty * 4 + i][k2];
#pragma unroll
            for (int i = 0; i < 4; i++) av[4 + i] = As2[64 + ty * 4 + i][k2];
#pragma unroll
            for (int i = 0; i < 4; i++) {
                acc00[i][0] = fdot2u(av[i], bv0.x, acc00[i][0]);
                acc00[i][1] = fdot2u(av[i], bv0.y, acc00[i][1]);
                acc00[i][2] = fdot2u(av[i], bv0.z, acc00[i][2]);
                acc00[i][3] = fdot2u(av[i], bv0.w, acc00[i][3]);
                acc01[i][0] = fdot2u(av[i], bv1.x, acc01[i][0]);
                acc01[i][1] = fdot2u(av[i], bv1.y, acc01[i][1]);
                acc01[i][2] = fdot2u(av[i], bv1.z, acc01[i][2]);
                acc01[i][3] = fdot2u(av[i], bv1.w, acc01[i][3]);
                acc10[i][0] = fdot2u(av[4 + i], bv0.x, acc10[i][0]);
                acc10[i][1] = fdot2u(av[4 + i], bv0.y, acc10[i][1]);
                acc10[i][2] = fdot2u(av[4 + i], bv0.z, acc10[i][2]);
                acc10[i][3] = fdot2u(av[4 + i], bv0.w, acc10[i][3]);
                acc11[i][0] = fdot2u(av[4 + i], bv1.x, acc11[i][0]);
                acc11[i][1] = fdot2u(av[4 + i], bv1.y, acc11[i][1]);
                acc11[i][2] = fdot2u(av[4 + i], bv1.z, acc11[i][2]);
                acc11[i][3] = fdot2u(av[4 + i], bv1.w, acc11[i][3]);
            }
        }
        __syncthreads();
    }

    float4 bb0 = *reinterpret_cast<const float4*>(&bias[tx * 4]);
    float4 bb1 = *reinterpret_cast<const float4*>(&bias[64 + tx * 4]);
#pragma unroll
    for (int i = 0; i < 4; i++) {
        int gr0 = rb + ty * 4 + i;
        int gr1 = rb + 64 + ty * 4 + i;
        float4 o00, o01, o10, o11;
        o00.x = acc00[i][0] + bb0.x; o00.y = acc00[i][1] + bb0.y; o00.z = acc00[i][2] + bb0.z; o00.w = acc00[i][3] + bb0.w;
        o01.x = acc01[i][0] + bb1.x; o01.y = acc01[i][1] + bb1.y; o01.z = acc01[i][2] + bb1.z; o01.w = acc01[i][3] + bb1.w;
        o10.x = acc10[i][0] + bb0.x; o10.y = acc10[i][1] + bb0.y; o10.z = acc10[i][2] + bb0.z; o10.w = acc10[i][3] + bb0.w;
        o11.x = acc11[i][0] + bb1.x; o11.y = acc11[i][1] + bb1.y; o11.z = acc11[i][2] + bb1.z; o11.w = acc11[i][3] + bb1.w;
        if (mat == 0) {
            if (gr0 < N_NODES) {
                uint2 u0, u1;
                u0.x = pack2(o00.x, o00.y); u0.y = pack2(o00.z, o00.w);
                u1.x = pack2(o01.x, o01.y); u1.y = pack2(o01.z, o01.w);
                *reinterpret_cast<uint2*>(&XLh[(size_t)gr0 * HC + tx * 4]) = u0;
                *reinterpret_cast<uint2*>(&XLh[(size_t)gr0 * HC + 64 + tx * 4]) = u1;
            }
            if (gr1 < N_NODES) {
                uint2 u0, u1;
                u0.x = pack2(o10.x, o10.y); u0.y = pack2(o10.z, o10.w);
                u1.x = pack2(o11.x, o11.y); u1.y = pack2(o11.z, o11.w);
                *reinterpret_cast<uint2*>(&XLh[(size_t)gr1 * HC + tx * 4]) = u0;
                *reinterpret_cast<uint2*>(&XLh[(size_t)gr1 * HC + 64 + tx * 4]) = u1;
            }
        } else {
            if (gr0 < N_NODES) {
                *reinterpret_cast<float4*>(&XR[(size_t)gr0 * HC + tx * 4]) = o00;
                *reinterpret_cast<float4*>(&XR[(size_t)gr0 * HC + 64 + tx * 4]) = o01;
            }
            if (gr1 < N_NODES) {
                *reinterpret_cast<float4*>(&XR[(size_t)gr1 * HC + tx * 4]) = o10;
                *reinterpret_cast<float4*>(&XR[(size_t)gr1 * HC + 64 + tx * 4]) = o11;
            }
        }
    }
}

// ---------------- Fused GAT: fp16 XL, 4 edges/wave, 16 lanes/edge ----------------

struct F8 { float v[8]; };

__device__ __forceinline__ F8 loadXL8(const char* XLb, int o) {
    uint4 ld = *reinterpret_cast<const uint4*>(XLb + (size_t)(unsigned)o);
    F8 r;
    __half2 h0 = *reinterpret_cast<__half2*>(&ld.x);
    __half2 h1 = *reinterpret_cast<__half2*>(&ld.y);
    __half2 h2 = *reinterpret_cast<__half2*>(&ld.z);
    __half2 h3 = *reinterpret_cast<__half2*>(&ld.w);
    float2 f0 = __half22float2(h0);
    float2 f1 = __half22float2(h1);
    float2 f2 = __half22float2(h2);
    float2 f3 = __half22float2(h3);
    r.v[0] = f0.x; r.v[1] = f0.y; r.v[2] = f1.x; r.v[3] = f1.y;
    r.v[4] = f2.x; r.v[5] = f2.y; r.v[6] = f3.x; r.v[7] = f3.y;
    return r;
}

__device__ __forceinline__ float score8(const F8& xl, const float* xr, const float* a) {
    float c = 0.f;
#pragma unroll
    for (int i = 0; i < 8; i++) {
        float h = xl.v[i] + xr[i];
        h = fmaxf(h, NEG_SLOPE * h);
        c = fmaf(a[i], h, c);
    }
    c += __shfl_xor(c, 1);
    c += __shfl_xor(c, 2);          // 4-lane head group holds e_h * log2e
    return fminf(c, 120.f);
}

__device__ __forceinline__ void upd8(float c, const F8& xl, float& z, float* acc) {
    float w = exp2f(c);
    z += w;
#pragma unroll
    for (int i = 0; i < 8; i++) acc[i] = fmaf(w, xl.v[i], acc[i]);
}

__global__ __launch_bounds__(256) void gat_fused_kernel(const __half* __restrict__ XLh,
    const float* __restrict__ XR, const float* __restrict__ att,
    const int* __restrict__ rowStart, const int* __restrict__ srcOff,
    const float* __restrict__ bvec, float* __restrict__ outF, __half* __restrict__ outH,
    int applyElu) {
    int wv = threadIdx.x >> 6;
    int l = threadIdx.x & 63;
    int q = l >> 4;
    int cl = l & 15;
    int n = blockIdx.x * 4 + wv;
    if (n >= N_NODES) return;
    int s0 = rowStart[n], s1 = rowStart[n + 1];

    float xr[8], a[8];
    {
        float4 x0 = *reinterpret_cast<const float4*>(&XR[(size_t)n * HC + 8 * cl]);
        float4 x1 = *reinterpret_cast<const float4*>(&XR[(size_t)n * HC + 8 * cl + 4]);
        float4 a0 = *reinterpret_cast<const float4*>(&att[8 * cl]);
        float4 a1 = *reinterpret_cast<const float4*>(&att[8 * cl + 4]);
        xr[0] = x0.x; xr[1] = x0.y; xr[2] = x0.z; xr[3] = x0.w;
        xr[4] = x1.x; xr[5] = x1.y; xr[6] = x1.z; xr[7] = x1.w;
        a[0] = a0.x * LOG2E; a[1] = a0.y * LOG2E; a[2] = a0.z * LOG2E; a[3] = a0.w * LOG2E;
        a[4] = a1.x * LOG2E; a[5] = a1.y * LOG2E; a[6] = a1.z * LOG2E; a[7] = a1.w * LOG2E;
    }
    const char* XLb = reinterpret_cast<const char*>(XLh) + 16 * cl;

    float z = 0.f;
    float acc[8];
#pragma unroll
    for (int i = 0; i < 8; i++) acc[i] = 0.f;

    int p = s0;
    for (; p + 16 <= s1; p += 16) {
        int oA = srcOff[p      + q];
        int oB = srcOff[p + 4  + q];
        int oC = srcOff[p + 8  + q];
        int oD = srcOff[p + 12 + q];
        F8 xA = loadXL8(XLb, oA);
        F8 xB = loadXL8(XLb, oB);
        F8 xC = loadXL8(XLb, oC);
        F8 xD = loadXL8(XLb, oD);
        float cA = score8(xA, xr, a);
        float cB = score8(xB, xr, a);
        float cC = score8(xC, xr, a);
        float cD = score8(xD, xr, a);
        upd8(cA, xA, z, acc);
        upd8(cB, xB, z, acc);
        upd8(cC, xC, z, acc);
        upd8(cD, xD, z, acc);
    }
    for (; p + 4 <= s1; p += 4) {
        int o = srcOff[p + q];
        F8 x = loadXL8(XLb, o);
        float c = score8(x, xr, a);
        upd8(c, x, z, acc);
    }
    if (p < s1) {
        int r = s1 - p;                         // 1..3 remaining
        int o = srcOff[min(p + q, s1 - 1)];     // clamped (no OOB), poisoned below
        F8 x = loadXL8(XLb, o);
        float c = score8(x, xr, a);
        if (q >= r) c = NEGBIG;                 // exp2 -> 0, contributes nothing
        upd8(c, x, z, acc);
    }

    z += __shfl_xor(z, 16);
    z += __shfl_xor(z, 32);
#pragma unroll
    for (int i = 0; i < 8; i++) {
        acc[i] += __shfl_xor(acc[i], 16);
        acc[i] += __shfl_xor(acc[i], 32);
    }

    if (q == 0) {
        float zinv = 1.f / z;
        float4 b0 = *reinterpret_cast<const float4*>(&bvec[8 * cl]);
        float4 b1 = *reinterpret_cast<const float4*>(&bvec[8 * cl + 4]);
        float o0[8];
        o0[0] = acc[0] * zinv + b0.x; o0[1] = acc[1] * zinv + b0.y;
        o0[2] = acc[2] * zinv + b0.z; o0[3] = acc[3] * zinv + b0.w;
        o0[4] = acc[4] * zinv + b1.x; o0[5] = acc[5] * zinv + b1.y;
        o0[6] = acc[6] * zinv + b1.z; o0[7] = acc[7] * zinv + b1.w;
        if (applyElu) {
#pragma unroll
            for (int i = 0; i < 8; i++) o0[i] = o0[i] > 0.f ? o0[i] : (__expf(o0[i]) - 1.f);
        }
        if (outH) {                 // intermediate layer: fp16 (feeds next GEMM)
            uint4 u;
            u.x = pack2(o0[0], o0[1]); u.y = pack2(o0[2], o0[3]);
            u.z = pack2(o0[4], o0[5]); u.w = pack2(o0[6], o0[7]);
            *reinterpret_cast<uint4*>(&outH[(size_t)n * HC + 8 * cl]) = u;
        } else {                    // final layer: fp32 d_out
            *reinterpret_cast<float4*>(&outF[(size_t)n * HC + 8 * cl]) = make_float4(o0[0], o0[1], o0[2], o0[3]);
            *reinterpret_cast<float4*>(&outF[(size_t)n * HC + 8 * cl + 4]) = make_float4(o0[4], o0[5], o0[6], o0[7]);
        }
    }
}

// ---------------- launch ----------------

extern "C" void kernel_launch(void* const* d_in, const int* in_sizes, int n_in,
                              void* d_out, int out_size, void* d_ws, size_t ws_size,
                              hipStream_t stream) {
    const float* x = (const float*)d_in[0];
    const int* ei = (const int*)d_in[1];
    const int* srcArr = ei;
    const int* dstArr = ei + N_EDGES;

    char* ws = (char*)d_ws;
    size_t off = 0;
    auto alloc = [&](size_t bytes) -> void* {
        void* p = ws + off;
        off = (off + bytes + 511) & ~(size_t)511;
        return p;
    };
    __half* xh     = (__half*)alloc((size_t)N_NODES * HC * 2);
    __half* Ph     = (__half*)alloc((size_t)N_NODES * HC * 2);
    __half* XLh    = (__half*)alloc((size_t)N_NODES * HC * 2);
    float* XR      = (float*)alloc((size_t)N_NODES * HC * 4);
    unsigned* Wp   = (unsigned*)alloc((size_t)2 * 64 * HC * 4);
    int* deg       = (int*)alloc((size_t)N_NODES * 4);
    int* rowStart  = (int*)alloc((size_t)(N_NODES + 1) * 4);
    int* blockSum  = (int*)alloc(64 * 4);
    int* blockOff  = (int*)alloc(64 * 4);
    int* bucketCur = (int*)alloc((size_t)NBUCKETS * 4);
    int* E         = (int*)alloc((size_t)ETOT * 4);
    int* srcOff    = (int*)alloc((size_t)ETOT * 4);

    const int NSCAN = (N_NODES + 1023) / 1024;   // 49

    hipMemsetAsync(deg, 0, (size_t)N_NODES * 4, stream);
    hist_kernel<<<(ETOT + 255) / 256, 256, 0, stream>>>(dstArr, deg);
    scanA_kernel<<<NSCAN, 1024, 0, stream>>>(deg, rowStart, blockSum);
    scanB_kernel<<<1, 64, 0, stream>>>(blockSum, blockOff, NSCAN);
    scanC_kernel<<<NSCAN, 1024, 0, stream>>>(rowStart, blockOff, bucketCur);
    chunk_scatter_kernel<<<NCHUNK, 256, 0, stream>>>(srcArr, dstArr, bucketCur, E);
    csr_scatter_kernel<<<NBUCKETS, 256, 0, stream>>>(E, rowStart, srcOff);
    cvt_x_kernel<<<(N_NODES * HC / 8 + 255) / 256, 256, 0, stream>>>(x, xh);

    for (int lyr = 0; lyr < 3; lyr++) {
        const __half* gin = (lyr == 0) ? xh : Ph;
        const float* Wl  = (const float*)d_in[2 + 6 * lyr + 0];
        const float* bl  = (const float*)d_in[2 + 6 * lyr + 1];
        const float* Wr  = (const float*)d_in[2 + 6 * lyr + 2];
        const float* br  = (const float*)d_in[2 + 6 * lyr + 3];
        const float* att = (const float*)d_in[2 + 6 * lyr + 4];
        const float* bb  = (const float*)d_in[2 + 6 * lyr + 5];

        pack_w_kernel<<<(2 * 64 * HC + 255) / 256, 256, 0, stream>>>(Wl, Wr, Wp);

        dim3 ggrid((N_NODES + 127) / 128, 2);
        gemm_kernel<<<ggrid, 256, 0, stream>>>(gin, Wp, bl, br, XLh, XR);

        int nb = (N_NODES + 3) / 4;
        gat_fused_kernel<<<nb, 256, 0, stream>>>(XLh, XR, att, rowStart, srcOff, bb,
                                                 lyr == 2 ? (float*)d_out : nullptr,
                                                 lyr < 2 ? Ph : nullptr,
                                                 lyr < 2 ? 1 : 0);
    }
}

// Round 14
// 430.567 us; speedup vs baseline: 1.4055x; 1.0569x over previous
//
#include <hip/hip_runtime.h>
#include <hip/hip_fp16.h>
#include <math.h>

#define N_NODES 50000
#define N_EDGES 1600000
#define ETOT (N_EDGES + N_NODES)
#define HC 128
#define HEADS 4
#define HID 32
#define NEG_SLOPE 0.2f
#define NPB 32                               // nodes per bucket (aligned)
#define NBUCKETS ((N_NODES + NPB - 1) / NPB) // 1563
#define CHUNK 8192
#define NCHUNK ((ETOT + CHUNK - 1) / CHUNK)  // 202
#define LOG2E 1.4426950408889634f
#define NEGBIG (-1e30f)

typedef _Float16 h2 __attribute__((ext_vector_type(2)));

__device__ __forceinline__ unsigned pack2(float a, float b) {
    return ((unsigned)__half_as_ushort(__float2half(b)) << 16) | __half_as_ushort(__float2half(a));
}

__device__ __forceinline__ float fdot2u(unsigned a, unsigned b, float c) {
#if __has_builtin(__builtin_amdgcn_fdot2)
    return __builtin_amdgcn_fdot2(__builtin_bit_cast(h2, a), __builtin_bit_cast(h2, b), c, false);
#else
    h2 ha = __builtin_bit_cast(h2, a);
    h2 hb = __builtin_bit_cast(h2, b);
    return fmaf((float)ha[0], (float)hb[0], fmaf((float)ha[1], (float)hb[1], c));
#endif
}

// ---------------- CSR build ----------------

__global__ __launch_bounds__(256) void hist_kernel(const int* __restrict__ dstArr, int* __restrict__ deg) {
    int i = blockIdx.x * 256 + threadIdx.x;
    if (i >= ETOT) return;
    int d = (i < N_EDGES) ? dstArr[i] : (i - N_EDGES);
    atomicAdd(&deg[d], 1);
}

__global__ __launch_bounds__(1024) void scanA_kernel(const int* __restrict__ deg,
                                                     int* __restrict__ rowStart, int* __restrict__ blockSum) {
    __shared__ int buf[1024];
    int i = blockIdx.x * 1024 + threadIdx.x;
    int v = (i < N_NODES) ? deg[i] : 0;
    buf[threadIdx.x] = v;
    __syncthreads();
    for (int off = 1; off < 1024; off <<= 1) {
        int t = (threadIdx.x >= off) ? buf[threadIdx.x - off] : 0;
        __syncthreads();
        buf[threadIdx.x] += t;
        __syncthreads();
    }
    if (i < N_NODES) rowStart[i] = buf[threadIdx.x] - v;   // exclusive, pre-offset
    if (threadIdx.x == 1023) blockSum[blockIdx.x] = buf[1023];
}

__global__ void scanB_kernel(const int* __restrict__ blockSum, int* __restrict__ blockOff, int nb) {
    if (threadIdx.x == 0 && blockIdx.x == 0) {
        int acc = 0;
        for (int j = 0; j < nb; j++) { blockOff[j] = acc; acc += blockSum[j]; }
    }
}

__global__ __launch_bounds__(1024) void scanC_kernel(int* __restrict__ rowStart, const int* __restrict__ blockOff,
                                                     int* __restrict__ bucketCursor) {
    int i = blockIdx.x * 1024 + threadIdx.x;
    if (i < N_NODES) {
        int v = rowStart[i] + blockOff[blockIdx.x];
        rowStart[i] = v;
        if ((i & (NPB - 1)) == 0) bucketCursor[i >> 5] = v;
    }
    if (i == 0) rowStart[N_NODES] = ETOT;   // sentinel
}

// Pass 1: chunked counting-sort scatter to bucket granularity.
__global__ __launch_bounds__(256) void chunk_scatter_kernel(const int* __restrict__ srcArr, const int* __restrict__ dstArr,
                                                            int* __restrict__ bucketCursor, int* __restrict__ E) {
    __shared__ int hist[NBUCKETS];   // then reused as running cursor
    int c0 = blockIdx.x * CHUNK;
    int c1 = min(c0 + CHUNK, ETOT);
    for (int b = threadIdx.x; b < NBUCKETS; b += 256) hist[b] = 0;
    __syncthreads();

    int myP[CHUNK / 256];   // packed src | (d<<16)
    int cnt = 0;
    for (int i = c0 + threadIdx.x; i < c1; i += 256) {
        int s, d;
        if (i < N_EDGES) { s = srcArr[i]; d = dstArr[i]; }
        else             { s = i - N_EDGES; d = s; }
        myP[cnt] = s | (d << 16);
        cnt++;
        atomicAdd(&hist[d >> 5], 1);
    }
    __syncthreads();
    for (int b = threadIdx.x; b < NBUCKETS; b += 256) {
        int h = hist[b];
        hist[b] = (h > 0) ? atomicAdd(&bucketCursor[b], h) : 0;
    }
    __syncthreads();
    for (int k = 0; k < cnt; k++) {
        int pe = myP[k];
        int pos = atomicAdd(&hist[((unsigned)pe) >> 21], 1);   // bucket = d>>5
        E[pos] = pe;
    }
}

// Pass 2: one block per bucket; emits BYTE offsets src*256 into srcOff (fp16 rows)
__global__ __launch_bounds__(256) void csr_scatter_kernel(const int* __restrict__ E, const int* __restrict__ rowStart,
                                                          int* __restrict__ srcOff) {
    __shared__ int lcur[NPB];
    int b = blockIdx.x;
    int n0 = b * NPB;
    int nend = min(n0 + NPB, N_NODES);
    if (threadIdx.x < nend - n0) lcur[threadIdx.x] = rowStart[n0 + threadIdx.x];
    __syncthreads();
    int e0 = rowStart[n0];
    int e1 = rowStart[nend];
    for (int i = e0 + threadIdx.x; i < e1; i += 256) {
        int pe = E[i];
        int pos = atomicAdd(&lcur[(pe >> 16) & (NPB - 1)], 1);
        srcOff[pos] = (pe & 0xFFFF) << 8;     // byte offset into XLh (row = 256 B fp16)
    }
}

// ---------------- fp16 prep: x -> xh, W -> k-interleaved half2 ----------------

__global__ __launch_bounds__(256) void cvt_x_kernel(const float* __restrict__ x, __half* __restrict__ xh) {
    int i = blockIdx.x * 256 + threadIdx.x;      // 8 halves per thread
    if (i >= N_NODES * HC / 8) return;
    const float4* s = reinterpret_cast<const float4*>(x + (size_t)i * 8);
    float4 v0 = s[0], v1 = s[1];
    uint4 o;
    o.x = pack2(v0.x, v0.y); o.y = pack2(v0.z, v0.w);
    o.z = pack2(v1.x, v1.y); o.w = pack2(v1.z, v1.w);
    reinterpret_cast<uint4*>(xh)[i] = o;
}

// Wp[mat][k2][n] = half2(W[2k2][n], W[2k2+1][n]);  mat 0=Wl 1=Wr
__global__ __launch_bounds__(256) void pack_w_kernel(const float* __restrict__ Wl, const float* __restrict__ Wr,
                                                     unsigned* __restrict__ Wp) {
    int i = blockIdx.x * 256 + threadIdx.x;      // 2*64*128 = 16384
    if (i >= 2 * 64 * HC) return;
    int mat = i >> 13;
    int k2 = (i >> 7) & 63;
    int n = i & 127;
    const float* W = mat ? Wr : Wl;
    Wp[i] = pack2(W[(2 * k2) * HC + n], W[(2 * k2 + 1) * HC + n]);
}

// ---------------- GEMM (fp16 dot2): 128x128 tile, 8x8/thread, K-step 32 ----------------
// grid = (ceil(N/128), 2); y=0: XLh (fp16) = in@Wl+bl, y=1: XR (fp32) = in@Wr+br.

__global__ __launch_bounds__(256) void gemm_kernel(const __half* __restrict__ xin,
    const unsigned* __restrict__ Wp, const float* __restrict__ bl, const float* __restrict__ br,
    __half* __restrict__ XLh, float* __restrict__ XR) {
    __shared__ unsigned As2[128][20];   // 16 half2 per row (+4 pad)
    __shared__ unsigned Bs2[16][132];   // [k2][n] half2 (+4 pad)
    int t = threadIdx.x;
    int rb = blockIdx.x * 128;
    int mat = blockIdx.y;
    const float* bias = mat ? br : bl;
    int tx = t & 15, ty = t >> 4;

    float acc00[4][4], acc01[4][4], acc10[4][4], acc11[4][4];
#pragma unroll
    for (int i = 0; i < 4; i++)
#pragma unroll
        for (int j = 0; j < 4; j++) { acc00[i][j] = 0.f; acc01[i][j] = 0.f; acc10[i][j] = 0.f; acc11[i][j] = 0.f; }

    for (int kt = 0; kt < 4; kt++) {
#pragma unroll
        for (int it = 0; it < 2; it++) {
            int idx = it * 256 + t;
            int r = idx >> 2, f = idx & 3;
            int gr = rb + r;
            uint4 v = make_uint4(0, 0, 0, 0);
            if (gr < N_NODES) v = *reinterpret_cast<const uint4*>(xin + (size_t)gr * HC + kt * 32 + f * 8);
            *reinterpret_cast<uint4*>(&As2[r][f * 4]) = v;
        }
#pragma unroll
        for (int it = 0; it < 2; it++) {
            int idx = it * 256 + t;
            int k2 = idx >> 5, f = idx & 31;
            *reinterpret_cast<uint4*>(&Bs2[k2][f * 4]) =
                *reinterpret_cast<const uint4*>(Wp + ((size_t)(mat * 64 + kt * 16 + k2) * HC + f * 4));
        }
        __syncthreads();
#pragma unroll
        for (int k2 = 0; k2 < 16; k2++) {
            uint4 bv0 = *reinterpret_cast<const uint4*>(&Bs2[k2][tx * 4]);
            uint4 bv1 = *reinterpret_cast<const uint4*>(&Bs2[k2][64 + tx * 4]);
            unsigned av[8];
#pragma unroll
            for (int i = 0; i < 4; i++) av[i] = As2[ty * 4 + i][k2];
#pragma unroll
            for (int i = 0; i < 4; i++) av[4 + i] = As2[64 + ty * 4 + i][k2];
#pragma unroll
            for (int i = 0; i < 4; i++) {
                acc00[i][0] = fdot2u(av[i], bv0.x, acc00[i][0]);
                acc00[i][1] = fdot2u(av[i], bv0.y, acc00[i][1]);
                acc00[i][2] = fdot2u(av[i], bv0.z, acc00[i][2]);
                acc00[i][3] = fdot2u(av[i], bv0.w, acc00[i][3]);
                acc01[i][0] = fdot2u(av[i], bv1.x, acc01[i][0]);
                acc01[i][1] = fdot2u(av[i], bv1.y, acc01[i][1]);
                acc01[i][2] = fdot2u(av[i], bv1.z, acc01[i][2]);
                acc01[i][3] = fdot2u(av[i], bv1.w, acc01[i][3]);
                acc10[i][0] = fdot2u(av[4 + i], bv0.x, acc10[i][0]);
                acc10[i][1] = fdot2u(av[4 + i], bv0.y, acc10[i][1]);
                acc10[i][2] = fdot2u(av[4 + i], bv0.z, acc10[i][2]);
                acc10[i][3] = fdot2u(av[4 + i], bv0.w, acc10[i][3]);
                acc11[i][0] = fdot2u(av[4 + i], bv1.x, acc11[i][0]);
                acc11[i][1] = fdot2u(av[4 + i], bv1.y, acc11[i][1]);
                acc11[i][2] = fdot2u(av[4 + i], bv1.z, acc11[i][2]);
                acc11[i][3] = fdot2u(av[4 + i], bv1.w, acc11[i][3]);
            }
        }
        __syncthreads();
    }

    float4 bb0 = *reinterpret_cast<const float4*>(&bias[tx * 4]);
    float4 bb1 = *reinterpret_cast<const float4*>(&bias[64 + tx * 4]);
#pragma unroll
    for (int i = 0; i < 4; i++) {
        int gr0 = rb + ty * 4 + i;
        int gr1 = rb + 64 + ty * 4 + i;
        float4 o00, o01, o10, o11;
        o00.x = acc00[i][0] + bb0.x; o00.y = acc00[i][1] + bb0.y; o00.z = acc00[i][2] + bb0.z; o00.w = acc00[i][3] + bb0.w;
        o01.x = acc01[i][0] + bb1.x; o01.y = acc01[i][1] + bb1.y; o01.z = acc01[i][2] + bb1.z; o01.w = acc01[i][3] + bb1.w;
        o10.x = acc10[i][0] + bb0.x; o10.y = acc10[i][1] + bb0.y; o10.z = acc10[i][2] + bb0.z; o10.w = acc10[i][3] + bb0.w;
        o11.x = acc11[i][0] + bb1.x; o11.y = acc11[i][1] + bb1.y; o11.z = acc11[i][2] + bb1.z; o11.w = acc11[i][3] + bb1.w;
        if (mat == 0) {
            if (gr0 < N_NODES) {
                uint2 u0, u1;
                u0.x = pack2(o00.x, o00.y); u0.y = pack2(o00.z, o00.w);
                u1.x = pack2(o01.x, o01.y); u1.y = pack2(o01.z, o01.w);
                *reinterpret_cast<uint2*>(&XLh[(size_t)gr0 * HC + tx * 4]) = u0;
                *reinterpret_cast<uint2*>(&XLh[(size_t)gr0 * HC + 64 + tx * 4]) = u1;
            }
            if (gr1 < N_NODES) {
                uint2 u0, u1;
                u0.x = pack2(o10.x, o10.y); u0.y = pack2(o10.z, o10.w);
                u1.x = pack2(o11.x, o11.y); u1.y = pack2(o11.z, o11.w);
                *reinterpret_cast<uint2*>(&XLh[(size_t)gr1 * HC + tx * 4]) = u0;
                *reinterpret_cast<uint2*>(&XLh[(size_t)gr1 * HC + 64 + tx * 4]) = u1;
            }
        } else {
            if (gr0 < N_NODES) {
                *reinterpret_cast<float4*>(&XR[(size_t)gr0 * HC + tx * 4]) = o00;
                *reinterpret_cast<float4*>(&XR[(size_t)gr0 * HC + 64 + tx * 4]) = o01;
            }
            if (gr1 < N_NODES) {
                *reinterpret_cast<float4*>(&XR[(size_t)gr1 * HC + tx * 4]) = o10;
                *reinterpret_cast<float4*>(&XR[(size_t)gr1 * HC + 64 + tx * 4]) = o11;
            }
        }
    }
}

// ---------------- Fused GAT: fp16 XL, packed-fp16 score, 4 edges/wave ----------------
// Lane l: q = l>>4 = edge slot (0..3); cl = l&15 covers channels [8cl, 8cl+8).
// Score path in packed fp16 via _Float16 ext-vectors (v_pk_add/mul/max_f16) +
// dot2 (fp32 acc). Value accumulation stays fp32 (direct-exp weights can exceed
// fp16 range); fmaf on extracted lanes fuses to v_fma_mix_f32.

__device__ __forceinline__ float score8p(uint4 xl, const unsigned* __restrict__ xrh,
                                         const unsigned* __restrict__ ah) {
    const h2 slope = { (_Float16)NEG_SLOPE, (_Float16)NEG_SLOPE };
    unsigned u[4] = { xl.x, xl.y, xl.z, xl.w };
    float c = 0.f;
#pragma unroll
    for (int j = 0; j < 4; j++) {
        h2 s = __builtin_bit_cast(h2, u[j]) + __builtin_bit_cast(h2, xrh[j]);
        h2 t = s * slope;
        h2 m = __builtin_elementwise_max(s, t);   // leaky-relu (slope < 1)
        c = fdot2u(__builtin_bit_cast(unsigned, m), ah[j], c);
    }
    c += __shfl_xor(c, 1);
    c += __shfl_xor(c, 2);          // 4-lane head group holds e_h * log2e
    return fminf(c, 120.f);
}

__device__ __forceinline__ void upd8p(float c, uint4 xl, float& z, float* __restrict__ acc) {
    float w = exp2f(c);
    z += w;
    unsigned u[4] = { xl.x, xl.y, xl.z, xl.w };
#pragma unroll
    for (int j = 0; j < 4; j++) {
        h2 h = __builtin_bit_cast(h2, u[j]);
        acc[2 * j]     = fmaf(w, (float)h[0], acc[2 * j]);
        acc[2 * j + 1] = fmaf(w, (float)h[1], acc[2 * j + 1]);
    }
}

__global__ __launch_bounds__(256) void gat_fused_kernel(const __half* __restrict__ XLh,
    const float* __restrict__ XR, const float* __restrict__ att,
    const int* __restrict__ rowStart, const int* __restrict__ srcOff,
    const float* __restrict__ bvec, float* __restrict__ outF, __half* __restrict__ outH,
    int applyElu) {
    int wv = threadIdx.x >> 6;
    int l = threadIdx.x & 63;
    int q = l >> 4;
    int cl = l & 15;
    int n = blockIdx.x * 4 + wv;
    if (n >= N_NODES) return;
    int s0 = rowStart[n], s1 = rowStart[n + 1];

    unsigned xrh[4], ah[4];
    {
        float4 x0 = *reinterpret_cast<const float4*>(&XR[(size_t)n * HC + 8 * cl]);
        float4 x1 = *reinterpret_cast<const float4*>(&XR[(size_t)n * HC + 8 * cl + 4]);
        float4 a0 = *reinterpret_cast<const float4*>(&att[8 * cl]);
        float4 a1 = *reinterpret_cast<const float4*>(&att[8 * cl + 4]);
        xrh[0] = pack2(x0.x, x0.y); xrh[1] = pack2(x0.z, x0.w);
        xrh[2] = pack2(x1.x, x1.y); xrh[3] = pack2(x1.z, x1.w);
        ah[0] = pack2(a0.x * LOG2E, a0.y * LOG2E); ah[1] = pack2(a0.z * LOG2E, a0.w * LOG2E);
        ah[2] = pack2(a1.x * LOG2E, a1.y * LOG2E); ah[3] = pack2(a1.z * LOG2E, a1.w * LOG2E);
    }
    const char* XLb = reinterpret_cast<const char*>(XLh) + 16 * cl;

    float z = 0.f;
    float acc[8];
#pragma unroll
    for (int i = 0; i < 8; i++) acc[i] = 0.f;

    int p = s0;
    // 16 edges per iteration: 4 gather instructions, each serving 4 edges
    for (; p + 16 <= s1; p += 16) {
        int oA = srcOff[p      + q];
        int oB = srcOff[p + 4  + q];
        int oC = srcOff[p + 8  + q];
        int oD = srcOff[p + 12 + q];
        uint4 xA = *reinterpret_cast<const uint4*>(XLb + (size_t)(unsigned)oA);
        uint4 xB = *reinterpret_cast<const uint4*>(XLb + (size_t)(unsigned)oB);
        uint4 xC = *reinterpret_cast<const uint4*>(XLb + (size_t)(unsigned)oC);
        uint4 xD = *reinterpret_cast<const uint4*>(XLb + (size_t)(unsigned)oD);
        float cA = score8p(xA, xrh, ah);
        float cB = score8p(xB, xrh, ah);
        float cC = score8p(xC, xrh, ah);
        float cD = score8p(xD, xrh, ah);
        upd8p(cA, xA, z, acc);
        upd8p(cB, xB, z, acc);
        upd8p(cC, xC, z, acc);
        upd8p(cD, xD, z, acc);
    }
    for (; p + 4 <= s1; p += 4) {
        int o = srcOff[p + q];
        uint4 x = *reinterpret_cast<const uint4*>(XLb + (size_t)(unsigned)o);
        float c = score8p(x, xrh, ah);
        upd8p(c, x, z, acc);
    }
    if (p < s1) {
        int r = s1 - p;                         // 1..3 remaining
        int o = srcOff[min(p + q, s1 - 1)];     // clamped (no OOB), poisoned below
        uint4 x = *reinterpret_cast<const uint4*>(XLb + (size_t)(unsigned)o);
        float c = score8p(x, xrh, ah);
        if (q >= r) c = NEGBIG;                 // exp2 -> 0, contributes nothing
        upd8p(c, x, z, acc);
    }

    // merge the 4 edge-slot partial sums (lanes 16/32 apart)
    z += __shfl_xor(z, 16);
    z += __shfl_xor(z, 32);
#pragma unroll
    for (int i = 0; i < 8; i++) {
        acc[i] += __shfl_xor(acc[i], 16);
        acc[i] += __shfl_xor(acc[i], 32);
    }

    if (q == 0) {
        float zinv = 1.f / z;
        float4 b0 = *reinterpret_cast<const float4*>(&bvec[8 * cl]);
        float4 b1 = *reinterpret_cast<const float4*>(&bvec[8 * cl + 4]);
        float o0[8];
        o0[0] = acc[0] * zinv + b0.x; o0[1] = acc[1] * zinv + b0.y;
        o0[2] = acc[2] * zinv + b0.z; o0[3] = acc[3] * zinv + b0.w;
        o0[4] = acc[4] * zinv + b1.x; o0[5] = acc[5] * zinv + b1.y;
        o0[6] = acc[6] * zinv + b1.z; o0[7] = acc[7] * zinv + b1.w;
        if (applyElu) {
#pragma unroll
            for (int i = 0; i < 8; i++) o0[i] = o0[i] > 0.f ? o0[i] : (__expf(o0[i]) - 1.f);
        }
        if (outH) {                 // intermediate layer: fp16 (feeds next GEMM)
            uint4 u;
            u.x = pack2(o0[0], o0[1]); u.y = pack2(o0[2], o0[3]);
            u.z = pack2(o0[4], o0[5]); u.w = pack2(o0[6], o0[7]);
            *reinterpret_cast<uint4*>(&outH[(size_t)n * HC + 8 * cl]) = u;
        } else {                    // final layer: fp32 d_out
            *reinterpret_cast<float4*>(&outF[(size_t)n * HC + 8 * cl]) = make_float4(o0[0], o0[1], o0[2], o0[3]);
            *reinterpret_cast<float4*>(&outF[(size_t)n * HC + 8 * cl + 4]) = make_float4(o0[4], o0[5], o0[6], o0[7]);
        }
    }
}

// ---------------- launch ----------------

extern "C" void kernel_launch(void* const* d_in, const int* in_sizes, int n_in,
                              void* d_out, int out_size, void* d_ws, size_t ws_size,
                              hipStream_t stream) {
    const float* x = (const float*)d_in[0];
    const int* ei = (const int*)d_in[1];
    const int* srcArr = ei;
    const int* dstArr = ei + N_EDGES;

    char* ws = (char*)d_ws;
    size_t off = 0;
    auto alloc = [&](size_t bytes) -> void* {
        void* p = ws + off;
        off = (off + bytes + 511) & ~(size_t)511;
        return p;
    };
    __half* xh     = (__half*)alloc((size_t)N_NODES * HC * 2);
    __half* Ph     = (__half*)alloc((size_t)N_NODES * HC * 2);
    __half* XLh    = (__half*)alloc((size_t)N_NODES * HC * 2);
    float* XR      = (float*)alloc((size_t)N_NODES * HC * 4);
    unsigned* Wp   = (unsigned*)alloc((size_t)2 * 64 * HC * 4);
    int* deg       = (int*)alloc((size_t)N_NODES * 4);
    int* rowStart  = (int*)alloc((size_t)(N_NODES + 1) * 4);
    int* blockSum  = (int*)alloc(64 * 4);
    int* blockOff  = (int*)alloc(64 * 4);
    int* bucketCur = (int*)alloc((size_t)NBUCKETS * 4);
    int* E         = (int*)alloc((size_t)ETOT * 4);
    int* srcOff    = (int*)alloc((size_t)ETOT * 4);

    const int NSCAN = (N_NODES + 1023) / 1024;   // 49

    (void)hipMemsetAsync(deg, 0, (size_t)N_NODES * 4, stream);
    hist_kernel<<<(ETOT + 255) / 256, 256, 0, stream>>>(dstArr, deg);
    scanA_kernel<<<NSCAN, 1024, 0, stream>>>(deg, rowStart, blockSum);
    scanB_kernel<<<1, 64, 0, stream>>>(blockSum, blockOff, NSCAN);
    scanC_kernel<<<NSCAN, 1024, 0, stream>>>(rowStart, blockOff, bucketCur);
    chunk_scatter_kernel<<<NCHUNK, 256, 0, stream>>>(srcArr, dstArr, bucketCur, E);
    csr_scatter_kernel<<<NBUCKETS, 256, 0, stream>>>(E, rowStart, srcOff);
    cvt_x_kernel<<<(N_NODES * HC / 8 + 255) / 256, 256, 0, stream>>>(x, xh);

    for (int lyr = 0; lyr < 3; lyr++) {
        const __half* gin = (lyr == 0) ? xh : Ph;
        const float* Wl  = (const float*)d_in[2 + 6 * lyr + 0];
        const float* bl  = (const float*)d_in[2 + 6 * lyr + 1];
        const float* Wr  = (const float*)d_in[2 + 6 * lyr + 2];
        const float* br  = (const float*)d_in[2 + 6 * lyr + 3];
        const float* att = (const float*)d_in[2 + 6 * lyr + 4];
        const float* bb  = (const float*)d_in[2 + 6 * lyr + 5];

        pack_w_kernel<<<(2 * 64 * HC + 255) / 256, 256, 0, stream>>>(Wl, Wr, Wp);

        dim3 ggrid((N_NODES + 127) / 128, 2);
        gemm_kernel<<<ggrid, 256, 0, stream>>>(gin, Wp, bl, br, XLh, XR);

        int nb = (N_NODES + 3) / 4;
        gat_fused_kernel<<<nb, 256, 0, stream>>>(XLh, XR, att, rowStart, srcOff, bb,
                                                 lyr == 2 ? (float*)d_out : nullptr,
                                                 lyr < 2 ? Ph : nullptr,
                                                 lyr < 2 ? 1 : 0);
    }
}

// Round 15
// 374.183 us; speedup vs baseline: 1.6172x; 1.1507x over previous
//
#include <hip/hip_runtime.h>
#include <hip/hip_fp16.h>
#include <math.h>

#define N_NODES 50000
#define N_EDGES 1600000
#define ETOT (N_EDGES + N_NODES)
#define HC 128
#define HEADS 4
#define HID 32
#define NEG_SLOPE 0.2f
#define NPB 32                               // nodes per bucket (aligned)
#define NBUCKETS ((N_NODES + NPB - 1) / NPB) // 1563
#define CHUNK 8192
#define NCHUNK ((ETOT + CHUNK - 1) / CHUNK)  // 202
#define LOG2E 1.4426950408889634f
#define NEGBIG (-1e30f)

typedef _Float16 h2 __attribute__((ext_vector_type(2)));

__device__ __forceinline__ unsigned pack2(float a, float b) {
    return ((unsigned)__half_as_ushort(__float2half(b)) << 16) | __half_as_ushort(__float2half(a));
}

__device__ __forceinline__ float fdot2u(unsigned a, unsigned b, float c) {
#if __has_builtin(__builtin_amdgcn_fdot2)
    return __builtin_amdgcn_fdot2(__builtin_bit_cast(h2, a), __builtin_bit_cast(h2, b), c, false);
#else
    h2 ha = __builtin_bit_cast(h2, a);
    h2 hb = __builtin_bit_cast(h2, b);
    return fmaf((float)ha[0], (float)hb[0], fmaf((float)ha[1], (float)hb[1], c));
#endif
}

// ---------------- CSR build (bucket-level only; no per-node histogram) ----------------

// Per-chunk LDS histogram over buckets; one global atomic per (chunk,bucket).
__global__ __launch_bounds__(256) void bucket_hist_kernel(const int* __restrict__ dstArr,
                                                          int* __restrict__ bucketCount) {
    __shared__ int hist[NBUCKETS];
    int c0 = blockIdx.x * CHUNK;
    int c1 = min(c0 + CHUNK, ETOT);
    for (int b = threadIdx.x; b < NBUCKETS; b += 256) hist[b] = 0;
    __syncthreads();
    for (int i = c0 + threadIdx.x; i < c1; i += 256) {
        int d = (i < N_EDGES) ? dstArr[i] : (i - N_EDGES);
        atomicAdd(&hist[d >> 5], 1);
    }
    __syncthreads();
    for (int b = threadIdx.x; b < NBUCKETS; b += 256) {
        int h = hist[b];
        if (h > 0) atomicAdd(&bucketCount[b], h);
    }
}

// Exclusive scan over 1563 bucket counts (single block) -> bucketStart + cursor copy.
__global__ __launch_bounds__(1024) void bucket_scan_kernel(const int* __restrict__ bucketCount,
                                                           int* __restrict__ bucketStart,
                                                           int* __restrict__ bucketCursor,
                                                           int* __restrict__ rowStart) {
    __shared__ int buf[1024];
    __shared__ int carry;
    if (threadIdx.x == 0) carry = 0;
    __syncthreads();
    for (int base = 0; base < NBUCKETS; base += 1024) {
        int i = base + threadIdx.x;
        int v = (i < NBUCKETS) ? bucketCount[i] : 0;
        buf[threadIdx.x] = v;
        __syncthreads();
        for (int off = 1; off < 1024; off <<= 1) {
            int t = (threadIdx.x >= off) ? buf[threadIdx.x - off] : 0;
            __syncthreads();
            buf[threadIdx.x] += t;
            __syncthreads();
        }
        if (i < NBUCKETS) {
            int excl = carry + buf[threadIdx.x] - v;
            bucketStart[i] = excl;
            bucketCursor[i] = excl;
        }
        __syncthreads();
        if (threadIdx.x == 1023) carry += buf[1023];
        __syncthreads();
    }
    if (threadIdx.x == 0) {
        bucketStart[NBUCKETS] = ETOT;
        rowStart[N_NODES] = ETOT;    // sentinel for gat_fused
    }
}

// Pass 1: chunked counting-sort scatter to bucket granularity.
__global__ __launch_bounds__(256) void chunk_scatter_kernel(const int* __restrict__ srcArr, const int* __restrict__ dstArr,
                                                            int* __restrict__ bucketCursor, int* __restrict__ E) {
    __shared__ int hist[NBUCKETS];   // then reused as running cursor
    int c0 = blockIdx.x * CHUNK;
    int c1 = min(c0 + CHUNK, ETOT);
    for (int b = threadIdx.x; b < NBUCKETS; b += 256) hist[b] = 0;
    __syncthreads();

    int myP[CHUNK / 256];   // packed src | (d<<16)
    int cnt = 0;
    for (int i = c0 + threadIdx.x; i < c1; i += 256) {
        int s, d;
        if (i < N_EDGES) { s = srcArr[i]; d = dstArr[i]; }
        else             { s = i - N_EDGES; d = s; }
        myP[cnt] = s | (d << 16);
        cnt++;
        atomicAdd(&hist[d >> 5], 1);
    }
    __syncthreads();
    for (int b = threadIdx.x; b < NBUCKETS; b += 256) {
        int h = hist[b];
        hist[b] = (h > 0) ? atomicAdd(&bucketCursor[b], h) : 0;
    }
    __syncthreads();
    for (int k = 0; k < cnt; k++) {
        int pe = myP[k];
        int pos = atomicAdd(&hist[((unsigned)pe) >> 21], 1);   // bucket = d>>5
        E[pos] = pe;
    }
}

// Pass 2: one block per bucket. Counts its <=32 local nodes from E (LDS only),
// derives rowStart by a serial 32-scan, then scatters byte offsets src*256.
__global__ __launch_bounds__(256) void csr_scatter_kernel(const int* __restrict__ E,
                                                          const int* __restrict__ bucketStart,
                                                          int* __restrict__ rowStart,
                                                          int* __restrict__ srcOff) {
    __shared__ int cnt[NPB];
    __shared__ int lcur[NPB];
    int b = blockIdx.x;
    int n0 = b * NPB;
    int e0 = bucketStart[b];
    int e1 = bucketStart[b + 1];
    if (threadIdx.x < NPB) cnt[threadIdx.x] = 0;
    __syncthreads();
    for (int i = e0 + threadIdx.x; i < e1; i += 256)
        atomicAdd(&cnt[(E[i] >> 16) & (NPB - 1)], 1);
    __syncthreads();
    if (threadIdx.x == 0) {          // serial scan over 32 entries
        int run = e0;
#pragma unroll
        for (int j = 0; j < NPB; j++) {
            lcur[j] = run;
            int n = n0 + j;
            if (n < N_NODES) rowStart[n] = run;
            run += cnt[j];
        }
    }
    __syncthreads();
    for (int i = e0 + threadIdx.x; i < e1; i += 256) {
        int pe = E[i];
        int pos = atomicAdd(&lcur[(pe >> 16) & (NPB - 1)], 1);
        srcOff[pos] = (pe & 0xFFFF) << 8;     // byte offset into XLh (row = 256 B fp16)
    }
}

// ---------------- fp16 prep: x -> xh, W -> k-interleaved half2 ----------------

__global__ __launch_bounds__(256) void cvt_x_kernel(const float* __restrict__ x, __half* __restrict__ xh) {
    int i = blockIdx.x * 256 + threadIdx.x;      // 8 halves per thread
    if (i >= N_NODES * HC / 8) return;
    const float4* s = reinterpret_cast<const float4*>(x + (size_t)i * 8);
    float4 v0 = s[0], v1 = s[1];
    uint4 o;
    o.x = pack2(v0.x, v0.y); o.y = pack2(v0.z, v0.w);
    o.z = pack2(v1.x, v1.y); o.w = pack2(v1.z, v1.w);
    reinterpret_cast<uint4*>(xh)[i] = o;
}

// Wp[mat][k2][n] = half2(W[2k2][n], W[2k2+1][n]);  mat 0=Wl 1=Wr
__global__ __launch_bounds__(256) void pack_w_kernel(const float* __restrict__ Wl, const float* __restrict__ Wr,
                                                     unsigned* __restrict__ Wp) {
    int i = blockIdx.x * 256 + threadIdx.x;      // 2*64*128 = 16384
    if (i >= 2 * 64 * HC) return;
    int mat = i >> 13;
    int k2 = (i >> 7) & 63;
    int n = i & 127;
    const float* W = mat ? Wr : Wl;
    Wp[i] = pack2(W[(2 * k2) * HC + n], W[(2 * k2 + 1) * HC + n]);
}

// ---------------- GEMM (fp16 dot2): 128x128 tile, 8x8/thread, K-step 32 ----------------
// grid = (ceil(N/128), 2); y=0: XLh (fp16) = in@Wl+bl, y=1: XR (fp32) = in@Wr+br.

__global__ __launch_bounds__(256) void gemm_kernel(const __half* __restrict__ xin,
    const unsigned* __restrict__ Wp, const float* __restrict__ bl, const float* __restrict__ br,
    __half* __restrict__ XLh, float* __restrict__ XR) {
    __shared__ unsigned As2[128][20];   // 16 half2 per row (+4 pad)
    __shared__ unsigned Bs2[16][132];   // [k2][n] half2 (+4 pad)
    int t = threadIdx.x;
    int rb = blockIdx.x * 128;
    int mat = blockIdx.y;
    const float* bias = mat ? br : bl;
    int tx = t & 15, ty = t >> 4;

    float acc00[4][4], acc01[4][4], acc10[4][4], acc11[4][4];
#pragma unroll
    for (int i = 0; i < 4; i++)
#pragma unroll
        for (int j = 0; j < 4; j++) { acc00[i][j] = 0.f; acc01[i][j] = 0.f; acc10[i][j] = 0.f; acc11[i][j] = 0.f; }

    for (int kt = 0; kt < 4; kt++) {
#pragma unroll
        for (int it = 0; it < 2; it++) {
            int idx = it * 256 + t;
            int r = idx >> 2, f = idx & 3;
            int gr = rb + r;
            uint4 v = make_uint4(0, 0, 0, 0);
            if (gr < N_NODES) v = *reinterpret_cast<const uint4*>(xin + (size_t)gr * HC + kt * 32 + f * 8);
            *reinterpret_cast<uint4*>(&As2[r][f * 4]) = v;
        }
#pragma unroll
        for (int it = 0; it < 2; it++) {
            int idx = it * 256 + t;
            int k2 = idx >> 5, f = idx & 31;
            *reinterpret_cast<uint4*>(&Bs2[k2][f * 4]) =
                *reinterpret_cast<const uint4*>(Wp + ((size_t)(mat * 64 + kt * 16 + k2) * HC + f * 4));
        }
        __syncthreads();
#pragma unroll
        for (int k2 = 0; k2 < 16; k2++) {
            uint4 bv0 = *reinterpret_cast<const uint4*>(&Bs2[k2][tx * 4]);
            uint4 bv1 = *reinterpret_cast<const uint4*>(&Bs2[k2][64 + tx * 4]);
            unsigned av[8];
#pragma unroll
            for (int i = 0; i < 4; i++) av[i] = As2[ty * 4 + i][k2];
#pragma unroll
            for (int i = 0; i < 4; i++) av[4 + i] = As2[64 + ty * 4 + i][k2];
#pragma unroll
            for (int i = 0; i < 4; i++) {
                acc00[i][0] = fdot2u(av[i], bv0.x, acc00[i][0]);
                acc00[i][1] = fdot2u(av[i], bv0.y, acc00[i][1]);
                acc00[i][2] = fdot2u(av[i], bv0.z, acc00[i][2]);
                acc00[i][3] = fdot2u(av[i], bv0.w, acc00[i][3]);
                acc01[i][0] = fdot2u(av[i], bv1.x, acc01[i][0]);
                acc01[i][1] = fdot2u(av[i], bv1.y, acc01[i][1]);
                acc01[i][2] = fdot2u(av[i], bv1.z, acc01[i][2]);
                acc01[i][3] = fdot2u(av[i], bv1.w, acc01[i][3]);
                acc10[i][0] = fdot2u(av[4 + i], bv0.x, acc10[i][0]);
                acc10[i][1] = fdot2u(av[4 + i], bv0.y, acc10[i][1]);
                acc10[i][2] = fdot2u(av[4 + i], bv0.z, acc10[i][2]);
                acc10[i][3] = fdot2u(av[4 + i], bv0.w, acc10[i][3]);
                acc11[i][0] = fdot2u(av[4 + i], bv1.x, acc11[i][0]);
                acc11[i][1] = fdot2u(av[4 + i], bv1.y, acc11[i][1]);
                acc11[i][2] = fdot2u(av[4 + i], bv1.z, acc11[i][2]);
                acc11[i][3] = fdot2u(av[4 + i], bv1.w, acc11[i][3]);
            }
        }
        __syncthreads();
    }

    float4 bb0 = *reinterpret_cast<const float4*>(&bias[tx * 4]);
    float4 bb1 = *reinterpret_cast<const float4*>(&bias[64 + tx * 4]);
#pragma unroll
    for (int i = 0; i < 4; i++) {
        int gr0 = rb + ty * 4 + i;
        int gr1 = rb + 64 + ty * 4 + i;
        float4 o00, o01, o10, o11;
        o00.x = acc00[i][0] + bb0.x; o00.y = acc00[i][1] + bb0.y; o00.z = acc00[i][2] + bb0.z; o00.w = acc00[i][3] + bb0.w;
        o01.x = acc01[i][0] + bb1.x; o01.y = acc01[i][1] + bb1.y; o01.z = acc01[i][2] + bb1.z; o01.w = acc01[i][3] + bb1.w;
        o10.x = acc10[i][0] + bb0.x; o10.y = acc10[i][1] + bb0.y; o10.z = acc10[i][2] + bb0.z; o10.w = acc10[i][3] + bb0.w;
        o11.x = acc11[i][0] + bb1.x; o11.y = acc11[i][1] + bb1.y; o11.z = acc11[i][2] + bb1.z; o11.w = acc11[i][3] + bb1.w;
        if (mat == 0) {
            if (gr0 < N_NODES) {
                uint2 u0, u1;
                u0.x = pack2(o00.x, o00.y); u0.y = pack2(o00.z, o00.w);
                u1.x = pack2(o01.x, o01.y); u1.y = pack2(o01.z, o01.w);
                *reinterpret_cast<uint2*>(&XLh[(size_t)gr0 * HC + tx * 4]) = u0;
                *reinterpret_cast<uint2*>(&XLh[(size_t)gr0 * HC + 64 + tx * 4]) = u1;
            }
            if (gr1 < N_NODES) {
                uint2 u0, u1;
                u0.x = pack2(o10.x, o10.y); u0.y = pack2(o10.z, o10.w);
                u1.x = pack2(o11.x, o11.y); u1.y = pack2(o11.z, o11.w);
                *reinterpret_cast<uint2*>(&XLh[(size_t)gr1 * HC + tx * 4]) = u0;
                *reinterpret_cast<uint2*>(&XLh[(size_t)gr1 * HC + 64 + tx * 4]) = u1;
            }
        } else {
            if (gr0 < N_NODES) {
                *reinterpret_cast<float4*>(&XR[(size_t)gr0 * HC + tx * 4]) = o00;
                *reinterpret_cast<float4*>(&XR[(size_t)gr0 * HC + 64 + tx * 4]) = o01;
            }
            if (gr1 < N_NODES) {
                *reinterpret_cast<float4*>(&XR[(size_t)gr1 * HC + tx * 4]) = o10;
                *reinterpret_cast<float4*>(&XR[(size_t)gr1 * HC + 64 + tx * 4]) = o11;
            }
        }
    }
}

// ---------------- Fused GAT: fp16 XL, packed-fp16 score, 4 edges/wave ----------------

__device__ __forceinline__ float score8p(uint4 xl, const unsigned* __restrict__ xrh,
                                         const unsigned* __restrict__ ah) {
    const h2 slope = { (_Float16)NEG_SLOPE, (_Float16)NEG_SLOPE };
    unsigned u[4] = { xl.x, xl.y, xl.z, xl.w };
    float c = 0.f;
#pragma unroll
    for (int j = 0; j < 4; j++) {
        h2 s = __builtin_bit_cast(h2, u[j]) + __builtin_bit_cast(h2, xrh[j]);
        h2 t = s * slope;
        h2 m = __builtin_elementwise_max(s, t);   // leaky-relu (slope < 1)
        c = fdot2u(__builtin_bit_cast(unsigned, m), ah[j], c);
    }
    c += __shfl_xor(c, 1);
    c += __shfl_xor(c, 2);          // 4-lane head group holds e_h * log2e
    return fminf(c, 120.f);
}

__device__ __forceinline__ void upd8p(float c, uint4 xl, float& z, float* __restrict__ acc) {
    float w = exp2f(c);
    z += w;
    unsigned u[4] = { xl.x, xl.y, xl.z, xl.w };
#pragma unroll
    for (int j = 0; j < 4; j++) {
        h2 h = __builtin_bit_cast(h2, u[j]);
        acc[2 * j]     = fmaf(w, (float)h[0], acc[2 * j]);
        acc[2 * j + 1] = fmaf(w, (float)h[1], acc[2 * j + 1]);
    }
}

__global__ __launch_bounds__(256) void gat_fused_kernel(const __half* __restrict__ XLh,
    const float* __restrict__ XR, const float* __restrict__ att,
    const int* __restrict__ rowStart, const int* __restrict__ srcOff,
    const float* __restrict__ bvec, float* __restrict__ outF, __half* __restrict__ outH,
    int applyElu) {
    int wv = threadIdx.x >> 6;
    int l = threadIdx.x & 63;
    int q = l >> 4;
    int cl = l & 15;
    int n = blockIdx.x * 4 + wv;
    if (n >= N_NODES) return;
    int s0 = rowStart[n], s1 = rowStart[n + 1];

    unsigned xrh[4], ah[4];
    {
        float4 x0 = *reinterpret_cast<const float4*>(&XR[(size_t)n * HC + 8 * cl]);
        float4 x1 = *reinterpret_cast<const float4*>(&XR[(size_t)n * HC + 8 * cl + 4]);
        float4 a0 = *reinterpret_cast<const float4*>(&att[8 * cl]);
        float4 a1 = *reinterpret_cast<const float4*>(&att[8 * cl + 4]);
        xrh[0] = pack2(x0.x, x0.y); xrh[1] = pack2(x0.z, x0.w);
        xrh[2] = pack2(x1.x, x1.y); xrh[3] = pack2(x1.z, x1.w);
        ah[0] = pack2(a0.x * LOG2E, a0.y * LOG2E); ah[1] = pack2(a0.z * LOG2E, a0.w * LOG2E);
        ah[2] = pack2(a1.x * LOG2E, a1.y * LOG2E); ah[3] = pack2(a1.z * LOG2E, a1.w * LOG2E);
    }
    const char* XLb = reinterpret_cast<const char*>(XLh) + 16 * cl;

    float z = 0.f;
    float acc[8];
#pragma unroll
    for (int i = 0; i < 8; i++) acc[i] = 0.f;

    int p = s0;
    // 16 edges per iteration: 4 gather instructions, each serving 4 edges
    for (; p + 16 <= s1; p += 16) {
        int oA = srcOff[p      + q];
        int oB = srcOff[p + 4  + q];
        int oC = srcOff[p + 8  + q];
        int oD = srcOff[p + 12 + q];
        uint4 xA = *reinterpret_cast<const uint4*>(XLb + (size_t)(unsigned)oA);
        uint4 xB = *reinterpret_cast<const uint4*>(XLb + (size_t)(unsigned)oB);
        uint4 xC = *reinterpret_cast<const uint4*>(XLb + (size_t)(unsigned)oC);
        uint4 xD = *reinterpret_cast<const uint4*>(XLb + (size_t)(unsigned)oD);
        float cA = score8p(xA, xrh, ah);
        float cB = score8p(xB, xrh, ah);
        float cC = score8p(xC, xrh, ah);
        float cD = score8p(xD, xrh, ah);
        upd8p(cA, xA, z, acc);
        upd8p(cB, xB, z, acc);
        upd8p(cC, xC, z, acc);
        upd8p(cD, xD, z, acc);
    }
    for (; p + 4 <= s1; p += 4) {
        int o = srcOff[p + q];
        uint4 x = *reinterpret_cast<const uint4*>(XLb + (size_t)(unsigned)o);
        float c = score8p(x, xrh, ah);
        upd8p(c, x, z, acc);
    }
    if (p < s1) {
        int r = s1 - p;                         // 1..3 remaining
        int o = srcOff[min(p + q, s1 - 1)];     // clamped (no OOB), poisoned below
        uint4 x = *reinterpret_cast<const uint4*>(XLb + (size_t)(unsigned)o);
        float c = score8p(x, xrh, ah);
        if (q >= r) c = NEGBIG;                 // exp2 -> 0, contributes nothing
        upd8p(c, x, z, acc);
    }

    // merge the 4 edge-slot partial sums (lanes 16/32 apart)
    z += __shfl_xor(z, 16);
    z += __shfl_xor(z, 32);
#pragma unroll
    for (int i = 0; i < 8; i++) {
        acc[i] += __shfl_xor(acc[i], 16);
        acc[i] += __shfl_xor(acc[i], 32);
    }

    if (q == 0) {
        float zinv = 1.f / z;
        float4 b0 = *reinterpret_cast<const float4*>(&bvec[8 * cl]);
        float4 b1 = *reinterpret_cast<const float4*>(&bvec[8 * cl + 4]);
        float o0[8];
        o0[0] = acc[0] * zinv + b0.x; o0[1] = acc[1] * zinv + b0.y;
        o0[2] = acc[2] * zinv + b0.z; o0[3] = acc[3] * zinv + b0.w;
        o0[4] = acc[4] * zinv + b1.x; o0[5] = acc[5] * zinv + b1.y;
        o0[6] = acc[6] * zinv + b1.z; o0[7] = acc[7] * zinv + b1.w;
        if (applyElu) {
#pragma unroll
            for (int i = 0; i < 8; i++) o0[i] = o0[i] > 0.f ? o0[i] : (__expf(o0[i]) - 1.f);
        }
        if (outH) {                 // intermediate layer: fp16 (feeds next GEMM)
            uint4 u;
            u.x = pack2(o0[0], o0[1]); u.y = pack2(o0[2], o0[3]);
            u.z = pack2(o0[4], o0[5]); u.w = pack2(o0[6], o0[7]);
            *reinterpret_cast<uint4*>(&outH[(size_t)n * HC + 8 * cl]) = u;
        } else {                    // final layer: fp32 d_out
            *reinterpret_cast<float4*>(&outF[(size_t)n * HC + 8 * cl]) = make_float4(o0[0], o0[1], o0[2], o0[3]);
            *reinterpret_cast<float4*>(&outF[(size_t)n * HC + 8 * cl + 4]) = make_float4(o0[4], o0[5], o0[6], o0[7]);
        }
    }
}

// ---------------- launch ----------------

extern "C" void kernel_launch(void* const* d_in, const int* in_sizes, int n_in,
                              void* d_out, int out_size, void* d_ws, size_t ws_size,
                              hipStream_t stream) {
    const float* x = (const float*)d_in[0];
    const int* ei = (const int*)d_in[1];
    const int* srcArr = ei;
    const int* dstArr = ei + N_EDGES;

    char* ws = (char*)d_ws;
    size_t off = 0;
    auto alloc = [&](size_t bytes) -> void* {
        void* p = ws + off;
        off = (off + bytes + 511) & ~(size_t)511;
        return p;
    };
    __half* xh      = (__half*)alloc((size_t)N_NODES * HC * 2);
    __half* Ph      = (__half*)alloc((size_t)N_NODES * HC * 2);
    __half* XLh     = (__half*)alloc((size_t)N_NODES * HC * 2);
    float* XR       = (float*)alloc((size_t)N_NODES * HC * 4);
    unsigned* Wp    = (unsigned*)alloc((size_t)2 * 64 * HC * 4);
    int* rowStart   = (int*)alloc((size_t)(N_NODES + 1) * 4);
    int* bucketCnt  = (int*)alloc((size_t)NBUCKETS * 4);
    int* bucketStart= (int*)alloc((size_t)(NBUCKETS + 1) * 4);
    int* bucketCur  = (int*)alloc((size_t)NBUCKETS * 4);
    int* E          = (int*)alloc((size_t)ETOT * 4);
    int* srcOff     = (int*)alloc((size_t)ETOT * 4);

    (void)hipMemsetAsync(bucketCnt, 0, (size_t)NBUCKETS * 4, stream);
    bucket_hist_kernel<<<NCHUNK, 256, 0, stream>>>(dstArr, bucketCnt);
    bucket_scan_kernel<<<1, 1024, 0, stream>>>(bucketCnt, bucketStart, bucketCur, rowStart);
    chunk_scatter_kernel<<<NCHUNK, 256, 0, stream>>>(srcArr, dstArr, bucketCur, E);
    csr_scatter_kernel<<<NBUCKETS, 256, 0, stream>>>(E, bucketStart, rowStart, srcOff);
    cvt_x_kernel<<<(N_NODES * HC / 8 + 255) / 256, 256, 0, stream>>>(x, xh);

    for (int lyr = 0; lyr < 3; lyr++) {
        const __half* gin = (lyr == 0) ? xh : Ph;
        const float* Wl  = (const float*)d_in[2 + 6 * lyr + 0];
        const float* bl  = (const float*)d_in[2 + 6 * lyr + 1];
        const float* Wr  = (const float*)d_in[2 + 6 * lyr + 2];
        const float* br  = (const float*)d_in[2 + 6 * lyr + 3];
        const float* att = (const float*)d_in[2 + 6 * lyr + 4];
        const float* bb  = (const float*)d_in[2 + 6 * lyr + 5];

        pack_w_kernel<<<(2 * 64 * HC + 255) / 256, 256, 0, stream>>>(Wl, Wr, Wp);

        dim3 ggrid((N_NODES + 127) / 128, 2);
        gemm_kernel<<<ggrid, 256, 0, stream>>>(gin, Wp, bl, br, XLh, XR);

        int nb = (N_NODES + 3) / 4;
        gat_fused_kernel<<<nb, 256, 0, stream>>>(XLh, XR, att, rowStart, srcOff, bb,
                                                 lyr == 2 ? (float*)d_out : nullptr,
                                                 lyr < 2 ? Ph : nullptr,
                                                 lyr < 2 ? 1 : 0);
    }
}

// Round 16
// 363.011 us; speedup vs baseline: 1.6670x; 1.0308x over previous
//
#include <hip/hip_runtime.h>
#include <hip/hip_fp16.h>
#include <math.h>

#define N_NODES 50000
#define N_EDGES 1600000
#define ETOT (N_EDGES + N_NODES)
#define HC 128
#define HEADS 4
#define HID 32
#define NEG_SLOPE 0.2f
#define NPB 32                               // nodes per bucket (aligned)
#define NBUCKETS ((N_NODES + NPB - 1) / NPB) // 1563
#define CHUNK 8192
#define NCHUNK ((ETOT + CHUNK - 1) / CHUNK)  // 202
#define LOG2E 1.4426950408889634f
#define NEGBIG (-1e30f)

// prep_kernel block ranges
#define CVTB (N_NODES * HC / 8 / 256)        // 3125
#define WB   (3 * 2 * 64 * HC / 256)         // 192
#define PREPB (CVTB + WB + 1 + NCHUNK)       // + att block + hist blocks

typedef _Float16 h2 __attribute__((ext_vector_type(2)));

__device__ __forceinline__ unsigned pack2(float a, float b) {
    return ((unsigned)__half_as_ushort(__float2half(b)) << 16) | __half_as_ushort(__float2half(a));
}

__device__ __forceinline__ float fdot2u(unsigned a, unsigned b, float c) {
#if __has_builtin(__builtin_amdgcn_fdot2)
    return __builtin_amdgcn_fdot2(__builtin_bit_cast(h2, a), __builtin_bit_cast(h2, b), c, false);
#else
    h2 ha = __builtin_bit_cast(h2, a);
    h2 hb = __builtin_bit_cast(h2, b);
    return fmaf((float)ha[0], (float)hb[0], fmaf((float)ha[1], (float)hb[1], c));
#endif
}

// ---------------- fused prep: cvt_x | pack_w(3 layers) | pack_att | bucket_hist ----------------

__global__ __launch_bounds__(256) void prep_kernel(const float* __restrict__ x, __half* __restrict__ xh,
    const float* __restrict__ Wl0, const float* __restrict__ Wr0,
    const float* __restrict__ Wl1, const float* __restrict__ Wr1,
    const float* __restrict__ Wl2, const float* __restrict__ Wr2,
    const float* __restrict__ att0, const float* __restrict__ att1, const float* __restrict__ att2,
    unsigned* __restrict__ Wp, unsigned* __restrict__ attp,
    const int* __restrict__ dstArr, int* __restrict__ bucketCount) {
    int b = blockIdx.x;
    if (b < CVTB) {
        int i = b * 256 + threadIdx.x;           // 8 halves per thread
        const float4* s = reinterpret_cast<const float4*>(x + (size_t)i * 8);
        float4 v0 = s[0], v1 = s[1];
        uint4 o;
        o.x = pack2(v0.x, v0.y); o.y = pack2(v0.z, v0.w);
        o.z = pack2(v1.x, v1.y); o.w = pack2(v1.z, v1.w);
        reinterpret_cast<uint4*>(xh)[i] = o;
        return;
    }
    b -= CVTB;
    if (b < WB) {
        // Wp[lyr][mat][k2][n] = half2(W[2k2][n], W[2k2+1][n])
        int i = b * 256 + threadIdx.x;           // 3*2*64*128 = 49152
        int lyr = i >> 14;
        int rem = i & 16383;
        int mat = rem >> 13;
        int k2 = (rem >> 7) & 63;
        int n = rem & 127;
        const float* Ws[6] = { Wl0, Wr0, Wl1, Wr1, Wl2, Wr2 };
        const float* W = Ws[lyr * 2 + mat];
        Wp[i] = pack2(W[(2 * k2) * HC + n], W[(2 * k2 + 1) * HC + n]);
        return;
    }
    b -= WB;
    if (b < 1) {
        // attp[lyr][j] = half2(att[2j], att[2j+1]) * log2e ; 3*64 = 192 entries
        int i = threadIdx.x;
        if (i < 3 * 64) {
            int lyr = i >> 6;
            int j = i & 63;
            const float* as[3] = { att0, att1, att2 };
            attp[i] = pack2(as[lyr][2 * j] * LOG2E, as[lyr][2 * j + 1] * LOG2E);
        }
        return;
    }
    b -= 1;
    {
        // bucket_hist: per-chunk LDS histogram over buckets
        __shared__ int hist[NBUCKETS];
        int c0 = b * CHUNK;
        int c1 = min(c0 + CHUNK, ETOT);
        for (int k = threadIdx.x; k < NBUCKETS; k += 256) hist[k] = 0;
        __syncthreads();
        for (int i = c0 + threadIdx.x; i < c1; i += 256) {
            int d = (i < N_EDGES) ? dstArr[i] : (i - N_EDGES);
            atomicAdd(&hist[d >> 5], 1);
        }
        __syncthreads();
        for (int k = threadIdx.x; k < NBUCKETS; k += 256) {
            int h = hist[k];
            if (h > 0) atomicAdd(&bucketCount[k], h);
        }
    }
}

// Exclusive scan over 1563 bucket counts (single block) -> bucketStart + cursor copy.
__global__ __launch_bounds__(1024) void bucket_scan_kernel(const int* __restrict__ bucketCount,
                                                           int* __restrict__ bucketStart,
                                                           int* __restrict__ bucketCursor,
                                                           int* __restrict__ rowStart) {
    __shared__ int buf[1024];
    __shared__ int carry;
    if (threadIdx.x == 0) carry = 0;
    __syncthreads();
    for (int base = 0; base < NBUCKETS; base += 1024) {
        int i = base + threadIdx.x;
        int v = (i < NBUCKETS) ? bucketCount[i] : 0;
        buf[threadIdx.x] = v;
        __syncthreads();
        for (int off = 1; off < 1024; off <<= 1) {
            int t = (threadIdx.x >= off) ? buf[threadIdx.x - off] : 0;
            __syncthreads();
            buf[threadIdx.x] += t;
            __syncthreads();
        }
        if (i < NBUCKETS) {
            int excl = carry + buf[threadIdx.x] - v;
            bucketStart[i] = excl;
            bucketCursor[i] = excl;
        }
        __syncthreads();
        if (threadIdx.x == 1023) carry += buf[1023];
        __syncthreads();
    }
    if (threadIdx.x == 0) {
        bucketStart[NBUCKETS] = ETOT;
        rowStart[N_NODES] = ETOT;    // sentinel for gat_fused
    }
}

// Pass 1: chunked counting-sort scatter to bucket granularity.
__global__ __launch_bounds__(256) void chunk_scatter_kernel(const int* __restrict__ srcArr, const int* __restrict__ dstArr,
                                                            int* __restrict__ bucketCursor, int* __restrict__ E) {
    __shared__ int hist[NBUCKETS];   // then reused as running cursor
    int c0 = blockIdx.x * CHUNK;
    int c1 = min(c0 + CHUNK, ETOT);
    for (int b = threadIdx.x; b < NBUCKETS; b += 256) hist[b] = 0;
    __syncthreads();

    int myP[CHUNK / 256];   // packed src | (d<<16)
    int cnt = 0;
    for (int i = c0 + threadIdx.x; i < c1; i += 256) {
        int s, d;
        if (i < N_EDGES) { s = srcArr[i]; d = dstArr[i]; }
        else             { s = i - N_EDGES; d = s; }
        myP[cnt] = s | (d << 16);
        cnt++;
        atomicAdd(&hist[d >> 5], 1);
    }
    __syncthreads();
    for (int b = threadIdx.x; b < NBUCKETS; b += 256) {
        int h = hist[b];
        hist[b] = (h > 0) ? atomicAdd(&bucketCursor[b], h) : 0;
    }
    __syncthreads();
    for (int k = 0; k < cnt; k++) {
        int pe = myP[k];
        int pos = atomicAdd(&hist[((unsigned)pe) >> 21], 1);   // bucket = d>>5
        E[pos] = pe;
    }
}

// Pass 2: one block per bucket. Counts its <=32 local nodes from E (LDS only),
// derives rowStart by a serial 32-scan, then scatters byte offsets src*256.
__global__ __launch_bounds__(256) void csr_scatter_kernel(const int* __restrict__ E,
                                                          const int* __restrict__ bucketStart,
                                                          int* __restrict__ rowStart,
                                                          int* __restrict__ srcOff) {
    __shared__ int cnt[NPB];
    __shared__ int lcur[NPB];
    int b = blockIdx.x;
    int n0 = b * NPB;
    int e0 = bucketStart[b];
    int e1 = bucketStart[b + 1];
    if (threadIdx.x < NPB) cnt[threadIdx.x] = 0;
    __syncthreads();
    for (int i = e0 + threadIdx.x; i < e1; i += 256)
        atomicAdd(&cnt[(E[i] >> 16) & (NPB - 1)], 1);
    __syncthreads();
    if (threadIdx.x == 0) {          // serial scan over 32 entries
        int run = e0;
#pragma unroll
        for (int j = 0; j < NPB; j++) {
            lcur[j] = run;
            int n = n0 + j;
            if (n < N_NODES) rowStart[n] = run;
            run += cnt[j];
        }
    }
    __syncthreads();
    for (int i = e0 + threadIdx.x; i < e1; i += 256) {
        int pe = E[i];
        int pos = atomicAdd(&lcur[(pe >> 16) & (NPB - 1)], 1);
        srcOff[pos] = (pe & 0xFFFF) << 8;     // byte offset into XLh (row = 256 B fp16)
    }
}

// ---------------- GEMM (fp16 dot2): 128x128 tile, 8x8/thread, K-step 32 ----------------
// grid = (ceil(N/128), 2); y=0: XLh = in@Wl+bl, y=1: XRh = in@Wr+br (both fp16).

__global__ __launch_bounds__(256) void gemm_kernel(const __half* __restrict__ xin,
    const unsigned* __restrict__ Wp, const float* __restrict__ bl, const float* __restrict__ br,
    __half* __restrict__ XLh, __half* __restrict__ XRh) {
    __shared__ unsigned As2[128][20];   // 16 half2 per row (+4 pad)
    __shared__ unsigned Bs2[16][132];   // [k2][n] half2 (+4 pad)
    int t = threadIdx.x;
    int rb = blockIdx.x * 128;
    int mat = blockIdx.y;
    const float* bias = mat ? br : bl;
    __half* dst = mat ? XRh : XLh;
    int tx = t & 15, ty = t >> 4;

    float acc00[4][4], acc01[4][4], acc10[4][4], acc11[4][4];
#pragma unroll
    for (int i = 0; i < 4; i++)
#pragma unroll
        for (int j = 0; j < 4; j++) { acc00[i][j] = 0.f; acc01[i][j] = 0.f; acc10[i][j] = 0.f; acc11[i][j] = 0.f; }

    for (int kt = 0; kt < 4; kt++) {
#pragma unroll
        for (int it = 0; it < 2; it++) {
            int idx = it * 256 + t;
            int r = idx >> 2, f = idx & 3;
            int gr = rb + r;
            uint4 v = make_uint4(0, 0, 0, 0);
            if (gr < N_NODES) v = *reinterpret_cast<const uint4*>(xin + (size_t)gr * HC + kt * 32 + f * 8);
            *reinterpret_cast<uint4*>(&As2[r][f * 4]) = v;
        }
#pragma unroll
        for (int it = 0; it < 2; it++) {
            int idx = it * 256 + t;
            int k2 = idx >> 5, f = idx & 31;
            *reinterpret_cast<uint4*>(&Bs2[k2][f * 4]) =
                *reinterpret_cast<const uint4*>(Wp + ((size_t)(mat * 64 + kt * 16 + k2) * HC + f * 4));
        }
        __syncthreads();
#pragma unroll
        for (int k2 = 0; k2 < 16; k2++) {
            uint4 bv0 = *reinterpret_cast<const uint4*>(&Bs2[k2][tx * 4]);
            uint4 bv1 = *reinterpret_cast<const uint4*>(&Bs2[k2][64 + tx * 4]);
            unsigned av[8];
#pragma unroll
            for (int i = 0; i < 4; i++) av[i] = As2[ty * 4 + i][k2];
#pragma unroll
            for (int i = 0; i < 4; i++) av[4 + i] = As2[64 + ty * 4 + i][k2];
#pragma unroll
            for (int i = 0; i < 4; i++) {
                acc00[i][0] = fdot2u(av[i], bv0.x, acc00[i][0]);
                acc00[i][1] = fdot2u(av[i], bv0.y, acc00[i][1]);
                acc00[i][2] = fdot2u(av[i], bv0.z, acc00[i][2]);
                acc00[i][3] = fdot2u(av[i], bv0.w, acc00[i][3]);
                acc01[i][0] = fdot2u(av[i], bv1.x, acc01[i][0]);
                acc01[i][1] = fdot2u(av[i], bv1.y, acc01[i][1]);
                acc01[i][2] = fdot2u(av[i], bv1.z, acc01[i][2]);
                acc01[i][3] = fdot2u(av[i], bv1.w, acc01[i][3]);
                acc10[i][0] = fdot2u(av[4 + i], bv0.x, acc10[i][0]);
                acc10[i][1] = fdot2u(av[4 + i], bv0.y, acc10[i][1]);
                acc10[i][2] = fdot2u(av[4 + i], bv0.z, acc10[i][2]);
                acc10[i][3] = fdot2u(av[4 + i], bv0.w, acc10[i][3]);
                acc11[i][0] = fdot2u(av[4 + i], bv1.x, acc11[i][0]);
                acc11[i][1] = fdot2u(av[4 + i], bv1.y, acc11[i][1]);
                acc11[i][2] = fdot2u(av[4 + i], bv1.z, acc11[i][2]);
                acc11[i][3] = fdot2u(av[4 + i], bv1.w, acc11[i][3]);
            }
        }
        __syncthreads();
    }

    float4 bb0 = *reinterpret_cast<const float4*>(&bias[tx * 4]);
    float4 bb1 = *reinterpret_cast<const float4*>(&bias[64 + tx * 4]);
#pragma unroll
    for (int i = 0; i < 4; i++) {
        int gr0 = rb + ty * 4 + i;
        int gr1 = rb + 64 + ty * 4 + i;
        if (gr0 < N_NODES) {
            uint2 u0, u1;
            u0.x = pack2(acc00[i][0] + bb0.x, acc00[i][1] + bb0.y);
            u0.y = pack2(acc00[i][2] + bb0.z, acc00[i][3] + bb0.w);
            u1.x = pack2(acc01[i][0] + bb1.x, acc01[i][1] + bb1.y);
            u1.y = pack2(acc01[i][2] + bb1.z, acc01[i][3] + bb1.w);
            *reinterpret_cast<uint2*>(&dst[(size_t)gr0 * HC + tx * 4]) = u0;
            *reinterpret_cast<uint2*>(&dst[(size_t)gr0 * HC + 64 + tx * 4]) = u1;
        }
        if (gr1 < N_NODES) {
            uint2 u0, u1;
            u0.x = pack2(acc10[i][0] + bb0.x, acc10[i][1] + bb0.y);
            u0.y = pack2(acc10[i][2] + bb0.z, acc10[i][3] + bb0.w);
            u1.x = pack2(acc11[i][0] + bb1.x, acc11[i][1] + bb1.y);
            u1.y = pack2(acc11[i][2] + bb1.z, acc11[i][3] + bb1.w);
            *reinterpret_cast<uint2*>(&dst[(size_t)gr1 * HC + tx * 4]) = u0;
            *reinterpret_cast<uint2*>(&dst[(size_t)gr1 * HC + 64 + tx * 4]) = u1;
        }
    }
}

// ---------------- Fused GAT: fp16 XL/XR, packed-fp16 score, 4 edges/wave ----------------

__device__ __forceinline__ float score8p(uint4 xl, const unsigned* __restrict__ xrh,
                                         const unsigned* __restrict__ ah) {
    const h2 slope = { (_Float16)NEG_SLOPE, (_Float16)NEG_SLOPE };
    unsigned u[4] = { xl.x, xl.y, xl.z, xl.w };
    float c = 0.f;
#pragma unroll
    for (int j = 0; j < 4; j++) {
        h2 s = __builtin_bit_cast(h2, u[j]) + __builtin_bit_cast(h2, xrh[j]);
        h2 t = s * slope;
        h2 m = __builtin_elementwise_max(s, t);   // leaky-relu (slope < 1)
        c = fdot2u(__builtin_bit_cast(unsigned, m), ah[j], c);
    }
    c += __shfl_xor(c, 1);
    c += __shfl_xor(c, 2);          // 4-lane head group holds e_h * log2e
    return fminf(c, 120.f);
}

__device__ __forceinline__ void upd8p(float c, uint4 xl, float& z, float* __restrict__ acc) {
    float w = exp2f(c);
    z += w;
    unsigned u[4] = { xl.x, xl.y, xl.z, xl.w };
#pragma unroll
    for (int j = 0; j < 4; j++) {
        h2 h = __builtin_bit_cast(h2, u[j]);
        acc[2 * j]     = fmaf(w, (float)h[0], acc[2 * j]);
        acc[2 * j + 1] = fmaf(w, (float)h[1], acc[2 * j + 1]);
    }
}

__global__ __launch_bounds__(256) void gat_fused_kernel(const __half* __restrict__ XLh,
    const __half* __restrict__ XRh, const unsigned* __restrict__ attp,
    const int* __restrict__ rowStart, const int* __restrict__ srcOff,
    const float* __restrict__ bvec, float* __restrict__ outF, __half* __restrict__ outH,
    int applyElu) {
    int wv = threadIdx.x >> 6;
    int l = threadIdx.x & 63;
    int q = l >> 4;
    int cl = l & 15;
    int n = blockIdx.x * 4 + wv;
    if (n >= N_NODES) return;
    int s0 = rowStart[n], s1 = rowStart[n + 1];

    uint4 xrv = *reinterpret_cast<const uint4*>(XRh + (size_t)n * HC + 8 * cl);
    uint4 av  = *reinterpret_cast<const uint4*>(attp + 4 * cl);
    unsigned xrh[4] = { xrv.x, xrv.y, xrv.z, xrv.w };
    unsigned ah[4]  = { av.x, av.y, av.z, av.w };
    const char* XLb = reinterpret_cast<const char*>(XLh) + 16 * cl;

    float z = 0.f;
    float acc[8];
#pragma unroll
    for (int i = 0; i < 8; i++) acc[i] = 0.f;

    int p = s0;
    // 16 edges per iteration: 4 gather instructions, each serving 4 edges
    for (; p + 16 <= s1; p += 16) {
        int oA = srcOff[p      + q];
        int oB = srcOff[p + 4  + q];
        int oC = srcOff[p + 8  + q];
        int oD = srcOff[p + 12 + q];
        uint4 xA = *reinterpret_cast<const uint4*>(XLb + (size_t)(unsigned)oA);
        uint4 xB = *reinterpret_cast<const uint4*>(XLb + (size_t)(unsigned)oB);
        uint4 xC = *reinterpret_cast<const uint4*>(XLb + (size_t)(unsigned)oC);
        uint4 xD = *reinterpret_cast<const uint4*>(XLb + (size_t)(unsigned)oD);
        float cA = score8p(xA, xrh, ah);
        float cB = score8p(xB, xrh, ah);
        float cC = score8p(xC, xrh, ah);
        float cD = score8p(xD, xrh, ah);
        upd8p(cA, xA, z, acc);
        upd8p(cB, xB, z, acc);
        upd8p(cC, xC, z, acc);
        upd8p(cD, xD, z, acc);
    }
    for (; p + 4 <= s1; p += 4) {
        int o = srcOff[p + q];
        uint4 x = *reinterpret_cast<const uint4*>(XLb + (size_t)(unsigned)o);
        float c = score8p(x, xrh, ah);
        upd8p(c, x, z, acc);
    }
    if (p < s1) {
        int r = s1 - p;                         // 1..3 remaining
        int o = srcOff[min(p + q, s1 - 1)];     // clamped (no OOB), poisoned below
        uint4 x = *reinterpret_cast<const uint4*>(XLb + (size_t)(unsigned)o);
        float c = score8p(x, xrh, ah);
        if (q >= r) c = NEGBIG;                 // exp2 -> 0, contributes nothing
        upd8p(c, x, z, acc);
    }

    // merge the 4 edge-slot partial sums (lanes 16/32 apart)
    z += __shfl_xor(z, 16);
    z += __shfl_xor(z, 32);
#pragma unroll
    for (int i = 0; i < 8; i++) {
        acc[i] += __shfl_xor(acc[i], 16);
        acc[i] += __shfl_xor(acc[i], 32);
    }

    if (q == 0) {
        float zinv = 1.f / z;
        float4 b0 = *reinterpret_cast<const float4*>(&bvec[8 * cl]);
        float4 b1 = *reinterpret_cast<const float4*>(&bvec[8 * cl + 4]);
        float o0[8];
        o0[0] = acc[0] * zinv + b0.x; o0[1] = acc[1] * zinv + b0.y;
        o0[2] = acc[2] * zinv + b0.z; o0[3] = acc[3] * zinv + b0.w;
        o0[4] = acc[4] * zinv + b1.x; o0[5] = acc[5] * zinv + b1.y;
        o0[6] = acc[6] * zinv + b1.z; o0[7] = acc[7] * zinv + b1.w;
        if (applyElu) {
#pragma unroll
            for (int i = 0; i < 8; i++) o0[i] = o0[i] > 0.f ? o0[i] : (__expf(o0[i]) - 1.f);
        }
        if (outH) {                 // intermediate layer: fp16 (feeds next GEMM)
            uint4 u;
            u.x = pack2(o0[0], o0[1]); u.y = pack2(o0[2], o0[3]);
            u.z = pack2(o0[4], o0[5]); u.w = pack2(o0[6], o0[7]);
            *reinterpret_cast<uint4*>(&outH[(size_t)n * HC + 8 * cl]) = u;
        } else {                    // final layer: fp32 d_out
            *reinterpret_cast<float4*>(&outF[(size_t)n * HC + 8 * cl]) = make_float4(o0[0], o0[1], o0[2], o0[3]);
            *reinterpret_cast<float4*>(&outF[(size_t)n * HC + 8 * cl + 4]) = make_float4(o0[4], o0[5], o0[6], o0[7]);
        }
    }
}

// ---------------- launch ----------------

extern "C" void kernel_launch(void* const* d_in, const int* in_sizes, int n_in,
                              void* d_out, int out_size, void* d_ws, size_t ws_size,
                              hipStream_t stream) {
    const float* x = (const float*)d_in[0];
    const int* ei = (const int*)d_in[1];
    const int* srcArr = ei;
    const int* dstArr = ei + N_EDGES;

    char* ws = (char*)d_ws;
    size_t off = 0;
    auto alloc = [&](size_t bytes) -> void* {
        void* p = ws + off;
        off = (off + bytes + 511) & ~(size_t)511;
        return p;
    };
    __half* xh      = (__half*)alloc((size_t)N_NODES * HC * 2);
    __half* Ph      = (__half*)alloc((size_t)N_NODES * HC * 2);
    __half* XLh     = (__half*)alloc((size_t)N_NODES * HC * 2);
    __half* XRh     = (__half*)alloc((size_t)N_NODES * HC * 2);
    unsigned* Wp    = (unsigned*)alloc((size_t)3 * 2 * 64 * HC * 4);
    unsigned* attp  = (unsigned*)alloc((size_t)3 * 64 * 4);
    int* rowStart   = (int*)alloc((size_t)(N_NODES + 1) * 4);
    int* bucketCnt  = (int*)alloc((size_t)NBUCKETS * 4);
    int* bucketStart= (int*)alloc((size_t)(NBUCKETS + 1) * 4);
    int* bucketCur  = (int*)alloc((size_t)NBUCKETS * 4);
    int* E          = (int*)alloc((size_t)ETOT * 4);
    int* srcOff     = (int*)alloc((size_t)ETOT * 4);

    (void)hipMemsetAsync(bucketCnt, 0, (size_t)NBUCKETS * 4, stream);
    prep_kernel<<<PREPB, 256, 0, stream>>>(x, xh,
        (const float*)d_in[2], (const float*)d_in[4],
        (const float*)d_in[8], (const float*)d_in[10],
        (const float*)d_in[14], (const float*)d_in[16],
        (const float*)d_in[6], (const float*)d_in[12], (const float*)d_in[18],
        Wp, attp, dstArr, bucketCnt);
    bucket_scan_kernel<<<1, 1024, 0, stream>>>(bucketCnt, bucketStart, bucketCur, rowStart);
    chunk_scatter_kernel<<<NCHUNK, 256, 0, stream>>>(srcArr, dstArr, bucketCur, E);
    csr_scatter_kernel<<<NBUCKETS, 256, 0, stream>>>(E, bucketStart, rowStart, srcOff);

    for (int lyr = 0; lyr < 3; lyr++) {
        const __half* gin = (lyr == 0) ? xh : Ph;
        const float* bl  = (const float*)d_in[2 + 6 * lyr + 1];
        const float* br  = (const float*)d_in[2 + 6 * lyr + 3];
        const float* bb  = (const float*)d_in[2 + 6 * lyr + 5];

        dim3 ggrid((N_NODES + 127) / 128, 2);
        gemm_kernel<<<ggrid, 256, 0, stream>>>(gin, Wp + (size_t)lyr * 2 * 64 * HC, bl, br, XLh, XRh);

        int nb = (N_NODES + 3) / 4;
        gat_fused_kernel<<<nb, 256, 0, stream>>>(XLh, XRh, attp + lyr * 64, rowStart, srcOff, bb,
                                                 lyr == 2 ? (float*)d_out : nullptr,
                                                 lyr < 2 ? Ph : nullptr,
                                                 lyr < 2 ? 1 : 0);
    }
}

// Round 17
// 360.329 us; speedup vs baseline: 1.6794x; 1.0074x over previous
//
#include <hip/hip_runtime.h>
#include <hip/hip_fp16.h>
#include <math.h>

#define N_NODES 50000
#define N_EDGES 1600000
#define ETOT (N_EDGES + N_NODES)
#define HC 128
#define HEADS 4
#define HID 32
#define NEG_SLOPE 0.2f
#define NPB 32                               // nodes per bucket (aligned)
#define NBUCKETS ((N_NODES + NPB - 1) / NPB) // 1563
#define CHUNK 8192
#define NCHUNK ((ETOT + CHUNK - 1) / CHUNK)  // 202
#define LOG2E 1.4426950408889634f
#define NEGBIG (-1e30f)

// prep_kernel block ranges
#define CVTB (N_NODES * HC / 8 / 256)        // 3125
#define WB   (3 * 2 * 64 * HC / 256)         // 192
#define PREPB (CVTB + WB + 1 + NCHUNK)

// gemm geometry
#define GX ((N_NODES + 127) / 128)           // 391
#define GEMM_SMEM (128 * 20 * 4 + 16 * 132 * 4)   // As2 + Bs2 = 18688 B

typedef _Float16 h2 __attribute__((ext_vector_type(2)));

__device__ __forceinline__ unsigned pack2(float a, float b) {
    return ((unsigned)__half_as_ushort(__float2half(b)) << 16) | __half_as_ushort(__float2half(a));
}

__device__ __forceinline__ float fdot2u(unsigned a, unsigned b, float c) {
#if __has_builtin(__builtin_amdgcn_fdot2)
    return __builtin_amdgcn_fdot2(__builtin_bit_cast(h2, a), __builtin_bit_cast(h2, b), c, false);
#else
    h2 ha = __builtin_bit_cast(h2, a);
    h2 hb = __builtin_bit_cast(h2, b);
    return fmaf((float)ha[0], (float)hb[0], fmaf((float)ha[1], (float)hb[1], c));
#endif
}

// ---------------- fused prep: cvt_x | pack_w(3 layers) | pack_att | bucket_hist ----------------

__global__ __launch_bounds__(256) void prep_kernel(const float* __restrict__ x, __half* __restrict__ xh,
    const float* __restrict__ Wl0, const float* __restrict__ Wr0,
    const float* __restrict__ Wl1, const float* __restrict__ Wr1,
    const float* __restrict__ Wl2, const float* __restrict__ Wr2,
    const float* __restrict__ att0, const float* __restrict__ att1, const float* __restrict__ att2,
    unsigned* __restrict__ Wp, unsigned* __restrict__ attp,
    const int* __restrict__ dstArr, int* __restrict__ bucketCount) {
    int b = blockIdx.x;
    if (b < CVTB) {
        int i = b * 256 + threadIdx.x;           // 8 halves per thread
        const float4* s = reinterpret_cast<const float4*>(x + (size_t)i * 8);
        float4 v0 = s[0], v1 = s[1];
        uint4 o;
        o.x = pack2(v0.x, v0.y); o.y = pack2(v0.z, v0.w);
        o.z = pack2(v1.x, v1.y); o.w = pack2(v1.z, v1.w);
        reinterpret_cast<uint4*>(xh)[i] = o;
        return;
    }
    b -= CVTB;
    if (b < WB) {
        int i = b * 256 + threadIdx.x;           // 3*2*64*128 = 49152
        int lyr = i >> 14;
        int rem = i & 16383;
        int mat = rem >> 13;
        int k2 = (rem >> 7) & 63;
        int n = rem & 127;
        const float* Ws[6] = { Wl0, Wr0, Wl1, Wr1, Wl2, Wr2 };
        const float* W = Ws[lyr * 2 + mat];
        Wp[i] = pack2(W[(2 * k2) * HC + n], W[(2 * k2 + 1) * HC + n]);
        return;
    }
    b -= WB;
    if (b < 1) {
        int i = threadIdx.x;
        if (i < 3 * 64) {
            int lyr = i >> 6;
            int j = i & 63;
            const float* as[3] = { att0, att1, att2 };
            attp[i] = pack2(as[lyr][2 * j] * LOG2E, as[lyr][2 * j + 1] * LOG2E);
        }
        return;
    }
    b -= 1;
    {
        __shared__ int hist[NBUCKETS];
        int c0 = b * CHUNK;
        int c1 = min(c0 + CHUNK, ETOT);
        for (int k = threadIdx.x; k < NBUCKETS; k += 256) hist[k] = 0;
        __syncthreads();
        for (int i = c0 + threadIdx.x; i < c1; i += 256) {
            int d = (i < N_EDGES) ? dstArr[i] : (i - N_EDGES);
            atomicAdd(&hist[d >> 5], 1);
        }
        __syncthreads();
        for (int k = threadIdx.x; k < NBUCKETS; k += 256) {
            int h = hist[k];
            if (h > 0) atomicAdd(&bucketCount[k], h);
        }
    }
}

// Exclusive scan over 1563 bucket counts (single block) -> bucketStart + cursor copy.
__global__ __launch_bounds__(1024) void bucket_scan_kernel(const int* __restrict__ bucketCount,
                                                           int* __restrict__ bucketStart,
                                                           int* __restrict__ bucketCursor,
                                                           int* __restrict__ rowStart) {
    __shared__ int buf[1024];
    __shared__ int carry;
    if (threadIdx.x == 0) carry = 0;
    __syncthreads();
    for (int base = 0; base < NBUCKETS; base += 1024) {
        int i = base + threadIdx.x;
        int v = (i < NBUCKETS) ? bucketCount[i] : 0;
        buf[threadIdx.x] = v;
        __syncthreads();
        for (int off = 1; off < 1024; off <<= 1) {
            int t = (threadIdx.x >= off) ? buf[threadIdx.x - off] : 0;
            __syncthreads();
            buf[threadIdx.x] += t;
            __syncthreads();
        }
        if (i < NBUCKETS) {
            int excl = carry + buf[threadIdx.x] - v;
            bucketStart[i] = excl;
            bucketCursor[i] = excl;
        }
        __syncthreads();
        if (threadIdx.x == 1023) carry += buf[1023];
        __syncthreads();
    }
    if (threadIdx.x == 0) {
        bucketStart[NBUCKETS] = ETOT;
        rowStart[N_NODES] = ETOT;    // sentinel for gat_fused
    }
}

// Pass 1: chunked counting-sort scatter to bucket granularity.
__global__ __launch_bounds__(256) void chunk_scatter_kernel(const int* __restrict__ srcArr, const int* __restrict__ dstArr,
                                                            int* __restrict__ bucketCursor, int* __restrict__ E) {
    __shared__ int hist[NBUCKETS];   // then reused as running cursor
    int c0 = blockIdx.x * CHUNK;
    int c1 = min(c0 + CHUNK, ETOT);
    for (int b = threadIdx.x; b < NBUCKETS; b += 256) hist[b] = 0;
    __syncthreads();

    int myP[CHUNK / 256];   // packed src | (d<<16)
    int cnt = 0;
    for (int i = c0 + threadIdx.x; i < c1; i += 256) {
        int s, d;
        if (i < N_EDGES) { s = srcArr[i]; d = dstArr[i]; }
        else             { s = i - N_EDGES; d = s; }
        myP[cnt] = s | (d << 16);
        cnt++;
        atomicAdd(&hist[d >> 5], 1);
    }
    __syncthreads();
    for (int b = threadIdx.x; b < NBUCKETS; b += 256) {
        int h = hist[b];
        hist[b] = (h > 0) ? atomicAdd(&bucketCursor[b], h) : 0;
    }
    __syncthreads();
    for (int k = 0; k < cnt; k++) {
        int pe = myP[k];
        int pos = atomicAdd(&hist[((unsigned)pe) >> 21], 1);   // bucket = d>>5
        E[pos] = pe;
    }
}

// ---------------- body: csr scatter (per bucket) ----------------
__device__ __forceinline__ void csr_body(char* smem, int b, const int* __restrict__ E,
                                         const int* __restrict__ bucketStart,
                                         int* __restrict__ rowStart, int* __restrict__ srcOff) {
    int* cnt  = reinterpret_cast<int*>(smem);
    int* lcur = cnt + NPB;
    int n0 = b * NPB;
    int e0 = bucketStart[b];
    int e1 = bucketStart[b + 1];
    if (threadIdx.x < NPB) cnt[threadIdx.x] = 0;
    __syncthreads();
    for (int i = e0 + threadIdx.x; i < e1; i += 256)
        atomicAdd(&cnt[(E[i] >> 16) & (NPB - 1)], 1);
    __syncthreads();
    if (threadIdx.x == 0) {          // serial scan over 32 entries
        int run = e0;
#pragma unroll
        for (int j = 0; j < NPB; j++) {
            lcur[j] = run;
            int n = n0 + j;
            if (n < N_NODES) rowStart[n] = run;
            run += cnt[j];
        }
    }
    __syncthreads();
    for (int i = e0 + threadIdx.x; i < e1; i += 256) {
        int pe = E[i];
        int pos = atomicAdd(&lcur[(pe >> 16) & (NPB - 1)], 1);
        srcOff[pos] = (pe & 0xFFFF) << 8;     // byte offset into XLh (row = 256 B fp16)
    }
}

// ---------------- body: GEMM (fp16 dot2), 128x128 tile, 8x8/thread, K-step 32 ----------------
__device__ __forceinline__ void gemm_body(char* smem, int rb, int mat,
    const __half* __restrict__ xin, const unsigned* __restrict__ Wp,
    const float* __restrict__ bias, __half* __restrict__ dst) {
    unsigned (*As2)[20]  = reinterpret_cast<unsigned(*)[20]>(smem);
    unsigned (*Bs2)[132] = reinterpret_cast<unsigned(*)[132]>(smem + 128 * 20 * 4);
    int t = threadIdx.x;
    int tx = t & 15, ty = t >> 4;

    float acc00[4][4], acc01[4][4], acc10[4][4], acc11[4][4];
#pragma unroll
    for (int i = 0; i < 4; i++)
#pragma unroll
        for (int j = 0; j < 4; j++) { acc00[i][j] = 0.f; acc01[i][j] = 0.f; acc10[i][j] = 0.f; acc11[i][j] = 0.f; }

    for (int kt = 0; kt < 4; kt++) {
#pragma unroll
        for (int it = 0; it < 2; it++) {
            int idx = it * 256 + t;
            int r = idx >> 2, f = idx & 3;
            int gr = rb + r;
            uint4 v = make_uint4(0, 0, 0, 0);
            if (gr < N_NODES) v = *reinterpret_cast<const uint4*>(xin + (size_t)gr * HC + kt * 32 + f * 8);
            *reinterpret_cast<uint4*>(&As2[r][f * 4]) = v;
        }
#pragma unroll
        for (int it = 0; it < 2; it++) {
            int idx = it * 256 + t;
            int k2 = idx >> 5, f = idx & 31;
            *reinterpret_cast<uint4*>(&Bs2[k2][f * 4]) =
                *reinterpret_cast<const uint4*>(Wp + ((size_t)(mat * 64 + kt * 16 + k2) * HC + f * 4));
        }
        __syncthreads();
#pragma unroll
        for (int k2 = 0; k2 < 16; k2++) {
            uint4 bv0 = *reinterpret_cast<const uint4*>(&Bs2[k2][tx * 4]);
            uint4 bv1 = *reinterpret_cast<const uint4*>(&Bs2[k2][64 + tx * 4]);
            unsigned av[8];
#pragma unroll
            for (int i = 0; i < 4; i++) av[i] = As2[ty * 4 + i][k2];
#pragma unroll
            for (int i = 0; i < 4; i++) av[4 + i] = As2[64 + ty * 4 + i][k2];
#pragma unroll
            for (int i = 0; i < 4; i++) {
                acc00[i][0] = fdot2u(av[i], bv0.x, acc00[i][0]);
                acc00[i][1] = fdot2u(av[i], bv0.y, acc00[i][1]);
                acc00[i][2] = fdot2u(av[i], bv0.z, acc00[i][2]);
                acc00[i][3] = fdot2u(av[i], bv0.w, acc00[i][3]);
                acc01[i][0] = fdot2u(av[i], bv1.x, acc01[i][0]);
                acc01[i][1] = fdot2u(av[i], bv1.y, acc01[i][1]);
                acc01[i][2] = fdot2u(av[i], bv1.z, acc01[i][2]);
                acc01[i][3] = fdot2u(av[i], bv1.w, acc01[i][3]);
                acc10[i][0] = fdot2u(av[4 + i], bv0.x, acc10[i][0]);
                acc10[i][1] = fdot2u(av[4 + i], bv0.y, acc10[i][1]);
                acc10[i][2] = fdot2u(av[4 + i], bv0.z, acc10[i][2]);
                acc10[i][3] = fdot2u(av[4 + i], bv0.w, acc10[i][3]);
                acc11[i][0] = fdot2u(av[4 + i], bv1.x, acc11[i][0]);
                acc11[i][1] = fdot2u(av[4 + i], bv1.y, acc11[i][1]);
                acc11[i][2] = fdot2u(av[4 + i], bv1.z, acc11[i][2]);
                acc11[i][3] = fdot2u(av[4 + i], bv1.w, acc11[i][3]);
            }
        }
        __syncthreads();
    }

    float4 bb0 = *reinterpret_cast<const float4*>(&bias[tx * 4]);
    float4 bb1 = *reinterpret_cast<const float4*>(&bias[64 + tx * 4]);
#pragma unroll
    for (int i = 0; i < 4; i++) {
        int gr0 = rb + ty * 4 + i;
        int gr1 = rb + 64 + ty * 4 + i;
        if (gr0 < N_NODES) {
            uint2 u0, u1;
            u0.x = pack2(acc00[i][0] + bb0.x, acc00[i][1] + bb0.y);
            u0.y = pack2(acc00[i][2] + bb0.z, acc00[i][3] + bb0.w);
            u1.x = pack2(acc01[i][0] + bb1.x, acc01[i][1] + bb1.y);
            u1.y = pack2(acc01[i][2] + bb1.z, acc01[i][3] + bb1.w);
            *reinterpret_cast<uint2*>(&dst[(size_t)gr0 * HC + tx * 4]) = u0;
            *reinterpret_cast<uint2*>(&dst[(size_t)gr0 * HC + 64 + tx * 4]) = u1;
        }
        if (gr1 < N_NODES) {
            uint2 u0, u1;
            u0.x = pack2(acc10[i][0] + bb0.x, acc10[i][1] + bb0.y);
            u0.y = pack2(acc10[i][2] + bb0.z, acc10[i][3] + bb0.w);
            u1.x = pack2(acc11[i][0] + bb1.x, acc11[i][1] + bb1.y);
            u1.y = pack2(acc11[i][2] + bb1.z, acc11[i][3] + bb1.w);
            *reinterpret_cast<uint2*>(&dst[(size_t)gr1 * HC + tx * 4]) = u0;
            *reinterpret_cast<uint2*>(&dst[(size_t)gr1 * HC + 64 + tx * 4]) = u1;
        }
    }
}

// standalone GEMM (layers 1,2)
__global__ __launch_bounds__(256) void gemm_kernel(const __half* __restrict__ xin,
    const unsigned* __restrict__ Wp, const float* __restrict__ bl, const float* __restrict__ br,
    __half* __restrict__ XLh, __half* __restrict__ XRh) {
    __shared__ alignas(16) char smem[GEMM_SMEM];
    int mat = blockIdx.y;
    gemm_body(smem, blockIdx.x * 128, mat, xin, Wp, mat ? br : bl, mat ? XRh : XLh);
}

// fused: csr_scatter (blocks 0..NBUCKETS-1) || layer-0 GEMM (remaining 2*GX blocks)
__global__ __launch_bounds__(256) void csr_gemm_kernel(const int* __restrict__ E,
    const int* __restrict__ bucketStart, int* __restrict__ rowStart, int* __restrict__ srcOff,
    const __half* __restrict__ xin, const unsigned* __restrict__ Wp,
    const float* __restrict__ bl, const float* __restrict__ br,
    __half* __restrict__ XLh, __half* __restrict__ XRh) {
    __shared__ alignas(16) char smem[GEMM_SMEM];
    if (blockIdx.x < NBUCKETS) {
        csr_body(smem, blockIdx.x, E, bucketStart, rowStart, srcOff);
        return;
    }
    int gb = blockIdx.x - NBUCKETS;
    int mat = (gb >= GX) ? 1 : 0;
    int bx = mat ? (gb - GX) : gb;
    gemm_body(smem, bx * 128, mat, xin, Wp, mat ? br : bl, mat ? XRh : XLh);
}

// ---------------- Fused GAT: fp16 XL/XR, packed-fp16 score, 4 edges/wave ----------------

__device__ __forceinline__ float score8p(uint4 xl, const unsigned* __restrict__ xrh,
                                         const unsigned* __restrict__ ah) {
    const h2 slope = { (_Float16)NEG_SLOPE, (_Float16)NEG_SLOPE };
    unsigned u[4] = { xl.x, xl.y, xl.z, xl.w };
    float c = 0.f;
#pragma unroll
    for (int j = 0; j < 4; j++) {
        h2 s = __builtin_bit_cast(h2, u[j]) + __builtin_bit_cast(h2, xrh[j]);
        h2 t = s * slope;
        h2 m = __builtin_elementwise_max(s, t);   // leaky-relu (slope < 1)
        c = fdot2u(__builtin_bit_cast(unsigned, m), ah[j], c);
    }
    c += __shfl_xor(c, 1);
    c += __shfl_xor(c, 2);          // 4-lane head group holds e_h * log2e
    return fminf(c, 120.f);
}

__device__ __forceinline__ void upd8p(float c, uint4 xl, float& z, float* __restrict__ acc) {
    float w = exp2f(c);
    z += w;
    unsigned u[4] = { xl.x, xl.y, xl.z, xl.w };
#pragma unroll
    for (int j = 0; j < 4; j++) {
        h2 h = __builtin_bit_cast(h2, u[j]);
        acc[2 * j]     = fmaf(w, (float)h[0], acc[2 * j]);
        acc[2 * j + 1] = fmaf(w, (float)h[1], acc[2 * j + 1]);
    }
}

__global__ __launch_bounds__(256) void gat_fused_kernel(const __half* __restrict__ XLh,
    const __half* __restrict__ XRh, const unsigned* __restrict__ attp,
    const int* __restrict__ rowStart, const int* __restrict__ srcOff,
    const float* __restrict__ bvec, float* __restrict__ outF, __half* __restrict__ outH,
    int applyElu) {
    int wv = threadIdx.x >> 6;
    int l = threadIdx.x & 63;
    int q = l >> 4;
    int cl = l & 15;
    int n = blockIdx.x * 4 + wv;
    if (n >= N_NODES) return;
    int s0 = rowStart[n], s1 = rowStart[n + 1];

    uint4 xrv = *reinterpret_cast<const uint4*>(XRh + (size_t)n * HC + 8 * cl);
    uint4 av  = *reinterpret_cast<const uint4*>(attp + 4 * cl);
    unsigned xrh[4] = { xrv.x, xrv.y, xrv.z, xrv.w };
    unsigned ah[4]  = { av.x, av.y, av.z, av.w };
    const char* XLb = reinterpret_cast<const char*>(XLh) + 16 * cl;

    float z = 0.f;
    float acc[8];
#pragma unroll
    for (int i = 0; i < 8; i++) acc[i] = 0.f;

    int p = s0;
    for (; p + 16 <= s1; p += 16) {
        int oA = srcOff[p      + q];
        int oB = srcOff[p + 4  + q];
        int oC = srcOff[p + 8  + q];
        int oD = srcOff[p + 12 + q];
        uint4 xA = *reinterpret_cast<const uint4*>(XLb + (size_t)(unsigned)oA);
        uint4 xB = *reinterpret_cast<const uint4*>(XLb + (size_t)(unsigned)oB);
        uint4 xC = *reinterpret_cast<const uint4*>(XLb + (size_t)(unsigned)oC);
        uint4 xD = *reinterpret_cast<const uint4*>(XLb + (size_t)(unsigned)oD);
        float cA = score8p(xA, xrh, ah);
        float cB = score8p(xB, xrh, ah);
        float cC = score8p(xC, xrh, ah);
        float cD = score8p(xD, xrh, ah);
        upd8p(cA, xA, z, acc);
        upd8p(cB, xB, z, acc);
        upd8p(cC, xC, z, acc);
        upd8p(cD, xD, z, acc);
    }
    for (; p + 4 <= s1; p += 4) {
        int o = srcOff[p + q];
        uint4 x = *reinterpret_cast<const uint4*>(XLb + (size_t)(unsigned)o);
        float c = score8p(x, xrh, ah);
        upd8p(c, x, z, acc);
    }
    if (p < s1) {
        int r = s1 - p;                         // 1..3 remaining
        int o = srcOff[min(p + q, s1 - 1)];     // clamped (no OOB), poisoned below
        uint4 x = *reinterpret_cast<const uint4*>(XLb + (size_t)(unsigned)o);
        float c = score8p(x, xrh, ah);
        if (q >= r) c = NEGBIG;                 // exp2 -> 0, contributes nothing
        upd8p(c, x, z, acc);
    }

    z += __shfl_xor(z, 16);
    z += __shfl_xor(z, 32);
#pragma unroll
    for (int i = 0; i < 8; i++) {
        acc[i] += __shfl_xor(acc[i], 16);
        acc[i] += __shfl_xor(acc[i], 32);
    }

    if (q == 0) {
        float zinv = 1.f / z;
        float4 b0 = *reinterpret_cast<const float4*>(&bvec[8 * cl]);
        float4 b1 = *reinterpret_cast<const float4*>(&bvec[8 * cl + 4]);
        float o0[8];
        o0[0] = acc[0] * zinv + b0.x; o0[1] = acc[1] * zinv + b0.y;
        o0[2] = acc[2] * zinv + b0.z; o0[3] = acc[3] * zinv + b0.w;
        o0[4] = acc[4] * zinv + b1.x; o0[5] = acc[5] * zinv + b1.y;
        o0[6] = acc[6] * zinv + b1.z; o0[7] = acc[7] * zinv + b1.w;
        if (applyElu) {
#pragma unroll
            for (int i = 0; i < 8; i++) o0[i] = o0[i] > 0.f ? o0[i] : (__expf(o0[i]) - 1.f);
        }
        if (outH) {                 // intermediate layer: fp16 (feeds next GEMM)
            uint4 u;
            u.x = pack2(o0[0], o0[1]); u.y = pack2(o0[2], o0[3]);
            u.z = pack2(o0[4], o0[5]); u.w = pack2(o0[6], o0[7]);
            *reinterpret_cast<uint4*>(&outH[(size_t)n * HC + 8 * cl]) = u;
        } else {                    // final layer: fp32 d_out
            *reinterpret_cast<float4*>(&outF[(size_t)n * HC + 8 * cl]) = make_float4(o0[0], o0[1], o0[2], o0[3]);
            *reinterpret_cast<float4*>(&outF[(size_t)n * HC + 8 * cl + 4]) = make_float4(o0[4], o0[5], o0[6], o0[7]);
        }
    }
}

// ---------------- launch ----------------

extern "C" void kernel_launch(void* const* d_in, const int* in_sizes, int n_in,
                              void* d_out, int out_size, void* d_ws, size_t ws_size,
                              hipStream_t stream) {
    const float* x = (const float*)d_in[0];
    const int* ei = (const int*)d_in[1];
    const int* srcArr = ei;
    const int* dstArr = ei + N_EDGES;

    char* ws = (char*)d_ws;
    size_t off = 0;
    auto alloc = [&](size_t bytes) -> void* {
        void* p = ws + off;
        off = (off + bytes + 511) & ~(size_t)511;
        return p;
    };
    __half* xh      = (__half*)alloc((size_t)N_NODES * HC * 2);
    __half* Ph      = (__half*)alloc((size_t)N_NODES * HC * 2);
    __half* XLh     = (__half*)alloc((size_t)N_NODES * HC * 2);
    __half* XRh     = (__half*)alloc((size_t)N_NODES * HC * 2);
    unsigned* Wp    = (unsigned*)alloc((size_t)3 * 2 * 64 * HC * 4);
    unsigned* attp  = (unsigned*)alloc((size_t)3 * 64 * 4);
    int* rowStart   = (int*)alloc((size_t)(N_NODES + 1) * 4);
    int* bucketCnt  = (int*)alloc((size_t)NBUCKETS * 4);
    int* bucketStart= (int*)alloc((size_t)(NBUCKETS + 1) * 4);
    int* bucketCur  = (int*)alloc((size_t)NBUCKETS * 4);
    int* E          = (int*)alloc((size_t)ETOT * 4);
    int* srcOff     = (int*)alloc((size_t)ETOT * 4);

    (void)hipMemsetAsync(bucketCnt, 0, (size_t)NBUCKETS * 4, stream);
    prep_kernel<<<PREPB, 256, 0, stream>>>(x, xh,
        (const float*)d_in[2], (const float*)d_in[4],
        (const float*)d_in[8], (const float*)d_in[10],
        (const float*)d_in[14], (const float*)d_in[16],
        (const float*)d_in[6], (const float*)d_in[12], (const float*)d_in[18],
        Wp, attp, dstArr, bucketCnt);
    bucket_scan_kernel<<<1, 1024, 0, stream>>>(bucketCnt, bucketStart, bucketCur, rowStart);
    chunk_scatter_kernel<<<NCHUNK, 256, 0, stream>>>(srcArr, dstArr, bucketCur, E);

    // fused: csr_scatter || layer-0 GEMM (independent work, one dispatch)
    csr_gemm_kernel<<<NBUCKETS + 2 * GX, 256, 0, stream>>>(E, bucketStart, rowStart, srcOff,
        xh, Wp, (const float*)d_in[3], (const float*)d_in[5], XLh, XRh);

    for (int lyr = 0; lyr < 3; lyr++) {
        const float* bb = (const float*)d_in[2 + 6 * lyr + 5];

        if (lyr > 0) {
            const float* bl = (const float*)d_in[2 + 6 * lyr + 1];
            const float* br = (const float*)d_in[2 + 6 * lyr + 3];
            dim3 ggrid(GX, 2);
            gemm_kernel<<<ggrid, 256, 0, stream>>>(Ph, Wp + (size_t)lyr * 2 * 64 * HC, bl, br, XLh, XRh);
        }

        int nb = (N_NODES + 3) / 4;
        gat_fused_kernel<<<nb, 256, 0, stream>>>(XLh, XRh, attp + lyr * 64, rowStart, srcOff, bb,
                                                 lyr == 2 ? (float*)d_out : nullptr,
                                                 lyr < 2 ? Ph : nullptr,
                                                 lyr < 2 ? 1 : 0);
    }
}